// Round 20
// baseline (87.640 us; speedup 1.0000x reference)
//
#include <hip/hip_runtime.h>
#include <math.h>

#define FD 128
#define GATES 4
#define NB   128           // edge chunks (per-chunk private histograms)
#define NRH  2             // hist node ranges
#define NRF  2             // fill node ranges
#define RSH_MAX 10016
#define RSF_MAX 10016
#define NMAX (RSH_MAX * 2)
#define LDW 68             // LDS tile row stride in uints (64 + 4 pad)

typedef __attribute__((ext_vector_type(8))) short bf16x8;
typedef __attribute__((ext_vector_type(4))) float f32x4;

__device__ __forceinline__ float sigmoidf_(float v) {
    return 1.0f / (1.0f + expf(-v));
}

__device__ __forceinline__ unsigned short f2bf(float f) {
    unsigned int u = __builtin_bit_cast(unsigned int, f);
    u += 0x7fffu + ((u >> 16) & 1u);           // RNE (finite values)
    return (unsigned short)(u >> 16);
}
__device__ __forceinline__ float bflo(unsigned int u) {
    return __builtin_bit_cast(float, u << 16);
}
__device__ __forceinline__ float bfhi(unsigned int u) {
    return __builtin_bit_cast(float, u & 0xffff0000u);
}
__device__ __forceinline__ unsigned int pack2bf(float lo, float hi) {
    return (unsigned int)f2bf(lo) | ((unsigned int)f2bf(hi) << 16);
}

// ---- Kernel 1: hist (NB*NRH blocks) || cvt (cvb blocks) || pack_w (64) ----
__global__ __launch_bounds__(512) void k_front(
    const float* __restrict__ ew, const int* __restrict__ src,
    const int* __restrict__ dst,
    float* __restrict__ deg_priv, unsigned short* __restrict__ cnt_priv,
    int* __restrict__ cursor, int* __restrict__ hflag,
    const float* __restrict__ x, const float* __restrict__ h,
    const float* __restrict__ Wx, const float* __restrict__ Wh,
    unsigned int* __restrict__ xw, unsigned int* __restrict__ hw,
    unsigned short* __restrict__ Wbf, int* __restrict__ flagpart,
    int E, int n, int ech, int rs, int n16, int cvb) {

    __shared__ float        degL[RSH_MAX];
    __shared__ unsigned int cntP[RSH_MAX / 2];

    const int bid  = blockIdx.x;
    const int tid  = threadIdx.x;
    const int lane = tid & 63;
    const int NH_BLOCKS = NB * NRH;

    if (bid < NH_BLOCKS) {
        // ---------------- hist section (2 edges / thread-iter) ----------------
        if (bid == 0 && tid == 0) { cursor[0] = 0; hflag[0] = 0; }

        const int b    = bid & (NB - 1);
        const int r    = bid >> 7;            // NB==128
        const int base = r * rs;
        const int rse  = min(rs, n - base);
        const int nh   = (rse + 1) >> 1;

        for (int i = tid; i < rse; i += 512) degL[i] = 0.f;
        for (int i = tid; i < nh;  i += 512) cntP[i] = 0u;
        __syncthreads();

        const int e0 = b * ech, e1 = min(e0 + ech, E);
        int e = e0 + tid * 2;
        for (; e + 1 < e1; e += 1024) {
            int2   s2 = *reinterpret_cast<const int2*>(src + e);
            int2   d2 = *reinterpret_cast<const int2*>(dst + e);
            float2 w2 = *reinterpret_cast<const float2*>(ew + e);
            unsigned int rs0 = (unsigned int)(s2.x - base);
            unsigned int rd0 = (unsigned int)(d2.x - base);
            unsigned int rs1 = (unsigned int)(s2.y - base);
            unsigned int rd1 = (unsigned int)(d2.y - base);
            if (rs0 < (unsigned int)rse) atomicAdd(&degL[rs0], w2.x);
            if (rd0 < (unsigned int)rse) atomicAdd(&cntP[rd0 >> 1], (rd0 & 1) ? 0x10000u : 1u);
            if (rs1 < (unsigned int)rse) atomicAdd(&degL[rs1], w2.y);
            if (rd1 < (unsigned int)rse) atomicAdd(&cntP[rd1 >> 1], (rd1 & 1) ? 0x10000u : 1u);
        }
        if (e < e1) {
            int s = src[e], d = dst[e];
            unsigned int rs_ = (unsigned int)(s - base);
            unsigned int rd_ = (unsigned int)(d - base);
            if (rs_ < (unsigned int)rse) atomicAdd(&degL[rs_], ew[e]);
            if (rd_ < (unsigned int)rse) atomicAdd(&cntP[rd_ >> 1], (rd_ & 1) ? 0x10000u : 1u);
        }
        __syncthreads();

        float*          dp = deg_priv + (size_t)b * n + base;
        unsigned short* cp = cnt_priv + (size_t)b * n + base;
        for (int i = tid; i < rse; i += 512) dp[i] = degL[i];
        for (int i = tid; i < rse; i += 512) {
            unsigned int v = cntP[i >> 1];
            cp[i] = (unsigned short)((i & 1) ? (v >> 16) : (v & 0xffffu));
        }
        return;
    }

    if (bid < NH_BLOCKS + cvb) {
        // ---------------- cvt section (rows only) ----------------
        int t = (bid - NH_BLOCKS) * 512 + tid;
        bool nz = false;
        if (t < n16) {
            const float4* xp = reinterpret_cast<const float4*>(x) + (size_t)t * 2;
            float4 a = xp[0], bq = xp[1];
            uint4 ox;
            ox.x = pack2bf(a.x, a.y);   ox.y = pack2bf(a.z, a.w);
            ox.z = pack2bf(bq.x, bq.y); ox.w = pack2bf(bq.z, bq.w);
            reinterpret_cast<uint4*>(xw)[t] = ox;

            const float4* hp = reinterpret_cast<const float4*>(h) + (size_t)t * 2;
            float4 hc = hp[0], hd = hp[1];
            nz = (hc.x != 0.f) | (hc.y != 0.f) | (hc.z != 0.f) | (hc.w != 0.f) |
                 (hd.x != 0.f) | (hd.y != 0.f) | (hd.z != 0.f) | (hd.w != 0.f);
            uint4 oh;
            oh.x = pack2bf(hc.x, hc.y); oh.y = pack2bf(hc.z, hc.w);
            oh.z = pack2bf(hd.x, hd.y); oh.w = pack2bf(hd.z, hd.w);
            reinterpret_cast<uint4*>(hw)[t] = oh;
        }
        __shared__ int fsh;
        if (tid == 0) fsh = 0;
        __syncthreads();
        unsigned long long m = __ballot(nz);
        if (lane == 0 && m) atomicOr(&fsh, 1);
        __syncthreads();
        if (tid == 0) flagpart[bid - NH_BLOCKS] = fsh;
        return;
    }

    // ---------------- pack_w section ----------------
    {
        int frag = (bid - NH_BLOCKS - cvb) * 8 + (tid >> 6);   // 0..511
        int cb = frag >> 4, kb = frag & 15;
        int col = cb * 16 + (lane & 15);
        int k0  = kb * 32 + (lane >> 4) * 8;

        int sel  = k0 >> 7;                // 0..3 : Wx0, Wx1, Wh0, Wh1
        int g    = col >> 7;
        int j    = col & (FD - 1);
        const float* Wb = (sel < 2) ? Wx : Wh;
        const float* p = Wb + (((size_t)g * 2 + (sel & 1)) * FD + (k0 & (FD - 1))) * FD + j;

        unsigned short outv[8];
        #pragma unroll
        for (int i = 0; i < 8; ++i) outv[i] = f2bf(p[(size_t)i * FD]);
        *reinterpret_cast<uint4*>(Wbf + (size_t)frag * 512 + lane * 8) =
            *reinterpret_cast<uint4*>(outv);
    }
}

// ---- Kernel 2: parallel fold (128 d's x 4 chunk-segments per block) ----
__global__ __launch_bounds__(512) void k_fold(
    const float* __restrict__ deg_priv, const unsigned short* __restrict__ cnt_priv,
    float* __restrict__ dis, int* __restrict__ cnt, int* __restrict__ off,
    int* __restrict__ curb, int* __restrict__ cursor, int n) {

    __shared__ float degp[4][128];
    __shared__ int   ctp[4][128];
    __shared__ int   offL[128];

    const int tid = threadIdx.x;
    const int seg = tid >> 7;          // 0..3 (32 chunks each)
    const int dl  = tid & 127;
    const int d   = blockIdx.x * 128 + dl;
    const int b0  = seg * 32;

    float s = 0.f; int ct = 0;
    if (d < n) {
        #pragma unroll 8
        for (int i = 0; i < 32; ++i) {
            int b = b0 + i;
            s  += deg_priv[(size_t)b * n + d];
            ct += (int)cnt_priv[(size_t)b * n + d];
        }
    }
    degp[seg][dl] = s;
    ctp[seg][dl]  = ct;
    __syncthreads();

    if (seg == 0) {
        int   ctt = 0;
        float st  = 0.f;
        #pragma unroll
        for (int q = 0; q < 4; ++q) { ctt += ctp[q][dl]; st += degp[q][dl]; }

        const int lane = tid & 63;
        int s_incl = (d < n) ? ctt : 0;
        #pragma unroll
        for (int o = 1; o < 64; o <<= 1) {
            int t2 = __shfl_up(s_incl, o);
            if (lane >= o) s_incl += t2;
        }
        int wtotal = __shfl(s_incl, 63);
        int base = 0;
        if (lane == 0) base = atomicAdd(cursor, wtotal);
        base = __shfl(base, 0);

        if (d < n) {
            dis[d] = (st > 0.0f) ? rsqrtf(fmaxf(st, 1e-12f)) : 0.0f;
            cnt[d] = ctt;
            int my0 = base + s_incl - ctt;
            off[d]   = my0;
            offL[dl] = my0;
        }
    }
    __syncthreads();

    if (d < n) {
        int run = offL[dl];
        for (int q = 0; q < seg; ++q) run += ctp[q][dl];
        #pragma unroll 8
        for (int i = 0; i < 32; ++i) {
            int b = b0 + i;
            curb[(size_t)b * n + d] = run;
            run += (int)cnt_priv[(size_t)b * n + d];
        }
    }
}

// ---- Kernel 3: bucket fill (2 edges / thread-iter); block 0: hflag OR ----
__global__ __launch_bounds__(512) void k_fill_lds(
    const float* __restrict__ ew, const int* __restrict__ src,
    const int* __restrict__ dst, const float* __restrict__ dis,
    const int* __restrict__ curb, int2* __restrict__ epk,
    const int* __restrict__ flagpart, int* __restrict__ hflag,
    int E, int n, int ech, int rs, int cvb) {

    __shared__ int curL[RSF_MAX];

    const int b    = blockIdx.x & (NB - 1);
    const int r    = blockIdx.x >> 7;
    const int base = r * rs;
    const int rse  = min(rs, n - base);

    if (blockIdx.x == 0) {
        int fl = 0;
        for (int i = threadIdx.x; i < cvb; i += 512) fl |= flagpart[i];
        unsigned long long m = __ballot(fl != 0);
        if ((threadIdx.x & 63) == 0 && m) atomicOr(hflag, 1);
    }

    const int* crow = curb + (size_t)b * n + base;
    for (int i = threadIdx.x; i < rse; i += 512) curL[i] = crow[i];
    __syncthreads();

    const int e0 = b * ech, e1 = min(e0 + ech, E);
    int e = e0 + (int)threadIdx.x * 2;
    for (; e + 1 < e1; e += 1024) {
        int2   s2 = *reinterpret_cast<const int2*>(src + e);
        int2   d2 = *reinterpret_cast<const int2*>(dst + e);
        float2 w2 = *reinterpret_cast<const float2*>(ew + e);
        unsigned int rd0 = (unsigned int)(d2.x - base);
        if (rd0 < (unsigned int)rse) {
            float w = -dis[s2.x] * w2.x * dis[d2.x];
            int p = atomicAdd(&curL[rd0], 1);
            epk[p] = make_int2(s2.x, __builtin_bit_cast(int, w));
        }
        unsigned int rd1 = (unsigned int)(d2.y - base);
        if (rd1 < (unsigned int)rse) {
            float w = -dis[s2.y] * w2.y * dis[d2.y];
            int p = atomicAdd(&curL[rd1], 1);
            epk[p] = make_int2(s2.y, __builtin_bit_cast(int, w));
        }
    }
    if (e < e1) {
        int d = dst[e];
        unsigned int rd_ = (unsigned int)(d - base);
        if (rd_ < (unsigned int)rse) {
            int s = src[e];
            float w = -dis[s] * ew[e] * dis[d];
            int p = atomicAdd(&curL[rd_], 1);
            epk[p] = make_int2(s, __builtin_bit_cast(int, w));
        }
    }
}

// ---- Kernel 4: gather -> writes tx/th ROWS (coalesced 256B per wave) ----
__global__ __launch_bounds__(256) void k_gather_bf(
    const unsigned int* __restrict__ xw, const unsigned int* __restrict__ hw,
    const int* __restrict__ off, const int* __restrict__ cntv,
    const int2* __restrict__ epk, const int* __restrict__ hflag,
    unsigned int* __restrict__ txw, unsigned int* __restrict__ thw, int n) {

    int d    = blockIdx.x * 4 + (threadIdx.x >> 6);
    int lane = threadIdx.x & 63;
    if (d >= n) return;
    const bool hasH = (*hflag) != 0;

    int p0 = off[d], p1 = p0 + cntv[d];
    float ax0 = 0.f, ax1 = 0.f, ah0 = 0.f, ah1 = 0.f;

    if (!hasH) {
        for (int base = p0; base < p1; base += 64) {
            int cnt = min(64, p1 - base);
            int2 my = make_int2(0, 0);
            if (lane < cnt) my = epk[base + lane];
            int   sm = my.x;
            float wm = __builtin_bit_cast(float, my.y);
            int k = 0;
            for (; k + 4 <= cnt; k += 4) {
                int   s0 = __shfl(sm, k),     s1 = __shfl(sm, k + 1);
                int   s2 = __shfl(sm, k + 2), s3 = __shfl(sm, k + 3);
                float w0 = __shfl(wm, k),     w1 = __shfl(wm, k + 1);
                float w2 = __shfl(wm, k + 2), w3 = __shfl(wm, k + 3);
                unsigned int u0 = xw[s0 * 64 + lane];
                unsigned int u1 = xw[s1 * 64 + lane];
                unsigned int u2 = xw[s2 * 64 + lane];
                unsigned int u3 = xw[s3 * 64 + lane];
                ax0 = fmaf(w0, bflo(u0), ax0); ax1 = fmaf(w0, bfhi(u0), ax1);
                ax0 = fmaf(w1, bflo(u1), ax0); ax1 = fmaf(w1, bfhi(u1), ax1);
                ax0 = fmaf(w2, bflo(u2), ax0); ax1 = fmaf(w2, bfhi(u2), ax1);
                ax0 = fmaf(w3, bflo(u3), ax0); ax1 = fmaf(w3, bfhi(u3), ax1);
            }
            for (; k < cnt; ++k) {
                int s = __shfl(sm, k);
                float w = __shfl(wm, k);
                unsigned int u = xw[s * 64 + lane];
                ax0 = fmaf(w, bflo(u), ax0); ax1 = fmaf(w, bfhi(u), ax1);
            }
        }
        txw[(size_t)d * 64 + lane] = pack2bf(ax0, ax1);
    } else {
        for (int base = p0; base < p1; base += 64) {
            int cnt = min(64, p1 - base);
            int2 my = make_int2(0, 0);
            if (lane < cnt) my = epk[base + lane];
            int   sm = my.x;
            float wm = __builtin_bit_cast(float, my.y);
            int k = 0;
            for (; k + 2 <= cnt; k += 2) {
                int   s0 = __shfl(sm, k), s1 = __shfl(sm, k + 1);
                float w0 = __shfl(wm, k), w1 = __shfl(wm, k + 1);
                unsigned int u0 = xw[s0 * 64 + lane];
                unsigned int v0 = hw[s0 * 64 + lane];
                unsigned int u1 = xw[s1 * 64 + lane];
                unsigned int v1 = hw[s1 * 64 + lane];
                ax0 = fmaf(w0, bflo(u0), ax0); ax1 = fmaf(w0, bfhi(u0), ax1);
                ah0 = fmaf(w0, bflo(v0), ah0); ah1 = fmaf(w0, bfhi(v0), ah1);
                ax0 = fmaf(w1, bflo(u1), ax0); ax1 = fmaf(w1, bfhi(u1), ax1);
                ah0 = fmaf(w1, bflo(v1), ah0); ah1 = fmaf(w1, bfhi(v1), ah1);
            }
            for (; k < cnt; ++k) {
                int s = __shfl(sm, k);
                float w = __shfl(wm, k);
                unsigned int u = xw[s * 64 + lane];
                unsigned int v = hw[s * 64 + lane];
                ax0 = fmaf(w, bflo(u), ax0); ax1 = fmaf(w, bfhi(u), ax1);
                ah0 = fmaf(w, bflo(v), ah0); ah1 = fmaf(w, bfhi(v), ah1);
            }
        }
        txw[(size_t)d * 64 + lane] = pack2bf(ax0, ax1);
        thw[(size_t)d * 64 + lane] = pack2bf(ah0, ah1);
    }
}

// ---- Kernel 5: GEMM+LSTM; 16-row tiles for max TLP ----
// Block = 16-row tile, 8 waves (1250 blocks, 10000 waves, ~9.8/SIMD).
// ldsR = raw rows (x then h), ldsG = gathered (tx then th).
// A-frag (kb): uint4 at lds[lane&15][(kb&3)*16+(lane>>4)*4]
__global__ __launch_bounds__(512) void k_gemm_lstm(
    const unsigned int* __restrict__ xw, const unsigned int* __restrict__ txw,
    const unsigned int* __restrict__ hw, const unsigned int* __restrict__ thw,
    const unsigned short* __restrict__ Wbf, const int* __restrict__ hflag,
    const float* __restrict__ c, const float* __restrict__ bias,
    const float* __restrict__ wc, float* __restrict__ out, int n) {

    __shared__ unsigned int ldsR[16][LDW];
    __shared__ unsigned int ldsG[16][LDW];

    const int rt   = blockIdx.x;
    const int tid  = threadIdx.x;
    const int jj   = tid >> 6;
    const int lane = tid & 63;
    const int r0   = rt * 16;
    const bool hasH = (*hflag) != 0;

    f32x4 acc[4];
    #pragma unroll
    for (int g = 0; g < 4; ++g) acc[g] = (f32x4)0.0f;

    // stage x + tx rows (each array: 16 rows x 64 uints = 256 uint4s)
    {
        int arr = tid >> 8;                  // 0 = ldsR(x), 1 = ldsG(tx)
        int sr  = (tid >> 4) & 15;
        int sc  = (tid & 15) * 4;
        uint4 v = make_uint4(0, 0, 0, 0);
        if (r0 + sr < n) {
            const unsigned int* srcp = arr ? txw : xw;
            v = *reinterpret_cast<const uint4*>(srcp + (size_t)(r0 + sr) * 64 + sc);
        }
        unsigned int* dstp = arr ? &ldsG[sr][sc] : &ldsR[sr][sc];
        *reinterpret_cast<uint4*>(dstp) = v;
    }
    __syncthreads();

    #pragma unroll
    for (int kb = 0; kb < 8; ++kb) {
        const int c0 = (kb & 3) * 16 + (lane >> 4) * 4;
        const unsigned int* lp = (kb < 4) ? &ldsR[lane & 15][c0]
                                          : &ldsG[lane & 15][c0];
        bf16x8 a = __builtin_bit_cast(bf16x8, *reinterpret_cast<const uint4*>(lp));
        #pragma unroll
        for (int g = 0; g < 4; ++g) {
            bf16x8 b = *reinterpret_cast<const bf16x8*>(
                Wbf + ((size_t)(g * 8 + jj) * 16 + kb) * 512 + lane * 8);
            acc[g] = __builtin_amdgcn_mfma_f32_16x16x32_bf16(a, b, acc[g], 0, 0, 0);
        }
    }

    if (hasH) {
        __syncthreads();
        {
            int arr = tid >> 8;
            int sr  = (tid >> 4) & 15;
            int sc  = (tid & 15) * 4;
            uint4 v = make_uint4(0, 0, 0, 0);
            if (r0 + sr < n) {
                const unsigned int* srcp = arr ? thw : hw;
                v = *reinterpret_cast<const uint4*>(srcp + (size_t)(r0 + sr) * 64 + sc);
            }
            unsigned int* dstp = arr ? &ldsG[sr][sc] : &ldsR[sr][sc];
            *reinterpret_cast<uint4*>(dstp) = v;
        }
        __syncthreads();

        #pragma unroll
        for (int kk = 0; kk < 8; ++kk) {
            const int kb = 8 + kk;
            const int c0 = (kk & 3) * 16 + (lane >> 4) * 4;
            const unsigned int* lp = (kk < 4) ? &ldsR[lane & 15][c0]
                                              : &ldsG[lane & 15][c0];
            bf16x8 a = __builtin_bit_cast(bf16x8, *reinterpret_cast<const uint4*>(lp));
            #pragma unroll
            for (int g = 0; g < 4; ++g) {
                bf16x8 b = *reinterpret_cast<const bf16x8*>(
                    Wbf + ((size_t)(g * 8 + jj) * 16 + kb) * 512 + lane * 8);
                acc[g] = __builtin_amdgcn_mfma_f32_16x16x32_bf16(a, b, acc[g], 0, 0, 0);
            }
        }
    }

    const int col  = jj * 16 + (lane & 15);
    const size_t NH = (size_t)n * FD;
    const float wc0 = wc[0 * FD + col], wc1 = wc[1 * FD + col], wc2 = wc[2 * FD + col];
    const float b0  = bias[0 * FD + col], b1 = bias[1 * FD + col];
    const float b2  = bias[2 * FD + col], b3 = bias[3 * FD + col];

    #pragma unroll
    for (int q = 0; q < 4; ++q) {
        int r = r0 + (lane >> 4) * 4 + q;
        if (r >= n) continue;
        float cv = c[(size_t)r * FD + col];
        float gi = acc[0][q] + wc0 * cv + b0;
        float gf = acc[1][q] + wc1 * cv + b1;
        float gg = acc[2][q] + b2;
        float iv = sigmoidf_(gi);
        float fv = sigmoidf_(gf);
        float cn = fv * cv + iv * tanhf(gg);
        float go = acc[3][q] + wc2 * cn + b3;
        float hn = sigmoidf_(go) * tanhf(cn);
        size_t o = (size_t)r * FD + col;
        out[o]          = hn;
        out[NH + o]     = hn;
        out[2 * NH + o] = cn;
    }
}

extern "C" void kernel_launch(void* const* d_in, const int* in_sizes, int n_in,
                              void* d_out, int out_size, void* d_ws, size_t ws_size,
                              hipStream_t stream) {
    const float* x   = (const float*)d_in[0];
    const float* ew  = (const float*)d_in[1];
    const float* h   = (const float*)d_in[2];
    const float* c   = (const float*)d_in[3];
    const float* Wx  = (const float*)d_in[4];
    const float* Wh  = (const float*)d_in[5];
    const float* b   = (const float*)d_in[6];
    const float* wc  = (const float*)d_in[7];
    const int*   src = (const int*)d_in[8];
    const int*   dst = (const int*)d_in[9];

    const int n = in_sizes[0] / FD;   // 20000  (<= NMAX)
    const int E = in_sizes[1];        // 640000

    const int Mpad = (n + 15) & ~15;              // 16-row tiles
    const int ech  = (E + NB - 1) / NB;           // 5000
    const int rsh  = (n + NRH - 1) / NRH;         // 10000
    const int rsf  = (n + NRF - 1) / NRF;         // 10000
    const int n16  = n * 16;
    const int cvb  = (n16 + 511) / 512;           // cvt section blocks
    const int npf  = (n + 127) / 128;             // fold blocks

    // ---- workspace layout ----
    float* dis      = (float*)d_ws;                        // n
    int*   cnt      = (int*)(dis + n);                     // n
    int*   off      = cnt + n;                             // n+4
    int*   hflag    = off + n + 4;                         // 4
    int*   cursor   = hflag + 4;                           // 4
    int*   flagpart = cursor + 4;                          // 1280 (pad)
    int2*  epk      = (int2*)(flagpart + 1280);            // E
    unsigned int* xw  = (unsigned int*)(epk + E);          // n*64
    unsigned int* hw  = xw + (size_t)n * 64;               // n*64
    unsigned int* txw = hw + (size_t)n * 64;               // n*64
    unsigned int* thw = txw + (size_t)n * 64;              // n*64
    unsigned short* Wbf = (unsigned short*)(thw + (size_t)n * 64); // 512*512
    int*   curb     = (int*)(Wbf + 512 * 512);             // NB*n
    float* deg_priv = (float*)(curb + (size_t)NB * n);     // NB*n
    unsigned short* cnt_priv = (unsigned short*)(deg_priv + (size_t)NB * n); // NB*n

    k_front<<<NB * NRH + cvb + 64, 512, 0, stream>>>(
        ew, src, dst, deg_priv, cnt_priv, cursor, hflag,
        x, h, Wx, Wh, xw, hw, Wbf, flagpart,
        E, n, ech, rsh, n16, cvb);
    k_fold<<<npf, 512, 0, stream>>>(deg_priv, cnt_priv, dis, cnt, off, curb,
                                    cursor, n);
    k_fill_lds<<<NB * NRF, 512, 0, stream>>>(ew, src, dst, dis, curb, epk,
                                             flagpart, hflag, E, n, ech, rsf, cvb);
    k_gather_bf<<<(n + 3) / 4, 256, 0, stream>>>(xw, hw, off, cnt, epk, hflag,
                                                 txw, thw, n);
    k_gemm_lstm<<<Mpad / 16, 512, 0, stream>>>(xw, txw, hw, thw, Wbf, hflag,
                                               c, b, wc, (float*)d_out, n);
}

// Round 21
// 84.875 us; speedup vs baseline: 1.0326x; 1.0326x over previous
//
#include <hip/hip_runtime.h>
#include <math.h>

#define FD 128
#define GATES 4
#define NB   128           // edge chunks (per-chunk private histograms)
#define NRH  2             // hist node ranges
#define NRF  2             // fill node ranges
#define RSH_MAX 10016
#define RSF_MAX 10016
#define NMAX (RSH_MAX * 2)
#define LDW 68             // LDS tile row stride in uints (64 + 4 pad)

typedef __attribute__((ext_vector_type(8))) short bf16x8;
typedef __attribute__((ext_vector_type(4))) float f32x4;

__device__ __forceinline__ float sigmoidf_(float v) {
    return 1.0f / (1.0f + expf(-v));
}

__device__ __forceinline__ unsigned short f2bf(float f) {
    unsigned int u = __builtin_bit_cast(unsigned int, f);
    u += 0x7fffu + ((u >> 16) & 1u);           // RNE (finite values)
    return (unsigned short)(u >> 16);
}
__device__ __forceinline__ float bflo(unsigned int u) {
    return __builtin_bit_cast(float, u << 16);
}
__device__ __forceinline__ float bfhi(unsigned int u) {
    return __builtin_bit_cast(float, u & 0xffff0000u);
}
__device__ __forceinline__ unsigned int pack2bf(float lo, float hi) {
    return (unsigned int)f2bf(lo) | ((unsigned int)f2bf(hi) << 16);
}

// ---- Kernel 1: hist (NB*NRH blocks) || cvt (cvb blocks) || pack_w (64) ----
__global__ __launch_bounds__(512) void k_front(
    const float* __restrict__ ew, const int* __restrict__ src,
    const int* __restrict__ dst,
    float* __restrict__ deg_priv, unsigned short* __restrict__ cnt_priv,
    int* __restrict__ cursor, int* __restrict__ hflag,
    const float* __restrict__ x, const float* __restrict__ h,
    const float* __restrict__ Wx, const float* __restrict__ Wh,
    unsigned int* __restrict__ xw, unsigned int* __restrict__ hw,
    unsigned short* __restrict__ Wbf, int* __restrict__ flagpart,
    int E, int n, int ech, int rs, int n16, int cvb) {

    __shared__ float        degL[RSH_MAX];
    __shared__ unsigned int cntP[RSH_MAX / 2];

    const int bid  = blockIdx.x;
    const int tid  = threadIdx.x;
    const int lane = tid & 63;
    const int NH_BLOCKS = NB * NRH;

    if (bid < NH_BLOCKS) {
        // ---------------- hist section (2 edges / thread-iter) ----------------
        if (bid == 0 && tid == 0) { cursor[0] = 0; hflag[0] = 0; }

        const int b    = bid & (NB - 1);
        const int r    = bid >> 7;            // NB==128
        const int base = r * rs;
        const int rse  = min(rs, n - base);
        const int nh   = (rse + 1) >> 1;

        for (int i = tid; i < rse; i += 512) degL[i] = 0.f;
        for (int i = tid; i < nh;  i += 512) cntP[i] = 0u;
        __syncthreads();

        const int e0 = b * ech, e1 = min(e0 + ech, E);
        int e = e0 + tid * 2;
        for (; e + 1 < e1; e += 1024) {
            int2   s2 = *reinterpret_cast<const int2*>(src + e);
            int2   d2 = *reinterpret_cast<const int2*>(dst + e);
            float2 w2 = *reinterpret_cast<const float2*>(ew + e);
            unsigned int rs0 = (unsigned int)(s2.x - base);
            unsigned int rd0 = (unsigned int)(d2.x - base);
            unsigned int rs1 = (unsigned int)(s2.y - base);
            unsigned int rd1 = (unsigned int)(d2.y - base);
            if (rs0 < (unsigned int)rse) atomicAdd(&degL[rs0], w2.x);
            if (rd0 < (unsigned int)rse) atomicAdd(&cntP[rd0 >> 1], (rd0 & 1) ? 0x10000u : 1u);
            if (rs1 < (unsigned int)rse) atomicAdd(&degL[rs1], w2.y);
            if (rd1 < (unsigned int)rse) atomicAdd(&cntP[rd1 >> 1], (rd1 & 1) ? 0x10000u : 1u);
        }
        if (e < e1) {
            int s = src[e], d = dst[e];
            unsigned int rs_ = (unsigned int)(s - base);
            unsigned int rd_ = (unsigned int)(d - base);
            if (rs_ < (unsigned int)rse) atomicAdd(&degL[rs_], ew[e]);
            if (rd_ < (unsigned int)rse) atomicAdd(&cntP[rd_ >> 1], (rd_ & 1) ? 0x10000u : 1u);
        }
        __syncthreads();

        float*          dp = deg_priv + (size_t)b * n + base;
        unsigned short* cp = cnt_priv + (size_t)b * n + base;
        for (int i = tid; i < rse; i += 512) dp[i] = degL[i];
        for (int i = tid; i < rse; i += 512) {
            unsigned int v = cntP[i >> 1];
            cp[i] = (unsigned short)((i & 1) ? (v >> 16) : (v & 0xffffu));
        }
        return;
    }

    if (bid < NH_BLOCKS + cvb) {
        // ---------------- cvt section (rows only) ----------------
        int t = (bid - NH_BLOCKS) * 512 + tid;
        bool nz = false;
        if (t < n16) {
            const float4* xp = reinterpret_cast<const float4*>(x) + (size_t)t * 2;
            float4 a = xp[0], bq = xp[1];
            uint4 ox;
            ox.x = pack2bf(a.x, a.y);   ox.y = pack2bf(a.z, a.w);
            ox.z = pack2bf(bq.x, bq.y); ox.w = pack2bf(bq.z, bq.w);
            reinterpret_cast<uint4*>(xw)[t] = ox;

            const float4* hp = reinterpret_cast<const float4*>(h) + (size_t)t * 2;
            float4 hc = hp[0], hd = hp[1];
            nz = (hc.x != 0.f) | (hc.y != 0.f) | (hc.z != 0.f) | (hc.w != 0.f) |
                 (hd.x != 0.f) | (hd.y != 0.f) | (hd.z != 0.f) | (hd.w != 0.f);
            uint4 oh;
            oh.x = pack2bf(hc.x, hc.y); oh.y = pack2bf(hc.z, hc.w);
            oh.z = pack2bf(hd.x, hd.y); oh.w = pack2bf(hd.z, hd.w);
            reinterpret_cast<uint4*>(hw)[t] = oh;
        }
        __shared__ int fsh;
        if (tid == 0) fsh = 0;
        __syncthreads();
        unsigned long long m = __ballot(nz);
        if (lane == 0 && m) atomicOr(&fsh, 1);
        __syncthreads();
        if (tid == 0) flagpart[bid - NH_BLOCKS] = fsh;
        return;
    }

    // ---------------- pack_w section ----------------
    {
        int frag = (bid - NH_BLOCKS - cvb) * 8 + (tid >> 6);   // 0..511
        int cb = frag >> 4, kb = frag & 15;
        int col = cb * 16 + (lane & 15);
        int k0  = kb * 32 + (lane >> 4) * 8;

        int sel  = k0 >> 7;                // 0..3 : Wx0, Wx1, Wh0, Wh1
        int g    = col >> 7;
        int j    = col & (FD - 1);
        const float* Wb = (sel < 2) ? Wx : Wh;
        const float* p = Wb + (((size_t)g * 2 + (sel & 1)) * FD + (k0 & (FD - 1))) * FD + j;

        unsigned short outv[8];
        #pragma unroll
        for (int i = 0; i < 8; ++i) outv[i] = f2bf(p[(size_t)i * FD]);
        *reinterpret_cast<uint4*>(Wbf + (size_t)frag * 512 + lane * 8) =
            *reinterpret_cast<uint4*>(outv);
    }
}

// ---- Kernel 2: parallel fold (128 d's x 4 chunk-segments per block) ----
__global__ __launch_bounds__(512) void k_fold(
    const float* __restrict__ deg_priv, const unsigned short* __restrict__ cnt_priv,
    float* __restrict__ dis, int* __restrict__ cnt, int* __restrict__ off,
    int* __restrict__ curb, int* __restrict__ cursor, int n) {

    __shared__ float degp[4][128];
    __shared__ int   ctp[4][128];
    __shared__ int   offL[128];

    const int tid = threadIdx.x;
    const int seg = tid >> 7;          // 0..3 (32 chunks each)
    const int dl  = tid & 127;
    const int d   = blockIdx.x * 128 + dl;
    const int b0  = seg * 32;

    float s = 0.f; int ct = 0;
    if (d < n) {
        #pragma unroll 8
        for (int i = 0; i < 32; ++i) {
            int b = b0 + i;
            s  += deg_priv[(size_t)b * n + d];
            ct += (int)cnt_priv[(size_t)b * n + d];
        }
    }
    degp[seg][dl] = s;
    ctp[seg][dl]  = ct;
    __syncthreads();

    if (seg == 0) {
        int   ctt = 0;
        float st  = 0.f;
        #pragma unroll
        for (int q = 0; q < 4; ++q) { ctt += ctp[q][dl]; st += degp[q][dl]; }

        const int lane = tid & 63;
        int s_incl = (d < n) ? ctt : 0;
        #pragma unroll
        for (int o = 1; o < 64; o <<= 1) {
            int t2 = __shfl_up(s_incl, o);
            if (lane >= o) s_incl += t2;
        }
        int wtotal = __shfl(s_incl, 63);
        int base = 0;
        if (lane == 0) base = atomicAdd(cursor, wtotal);
        base = __shfl(base, 0);

        if (d < n) {
            dis[d] = (st > 0.0f) ? rsqrtf(fmaxf(st, 1e-12f)) : 0.0f;
            cnt[d] = ctt;
            int my0 = base + s_incl - ctt;
            off[d]   = my0;
            offL[dl] = my0;
        }
    }
    __syncthreads();

    if (d < n) {
        int run = offL[dl];
        for (int q = 0; q < seg; ++q) run += ctp[q][dl];
        #pragma unroll 8
        for (int i = 0; i < 32; ++i) {
            int b = b0 + i;
            curb[(size_t)b * n + d] = run;
            run += (int)cnt_priv[(size_t)b * n + d];
        }
    }
}

// ---- Kernel 3: bucket fill (2 edges / thread-iter); block 0: hflag OR ----
__global__ __launch_bounds__(512) void k_fill_lds(
    const float* __restrict__ ew, const int* __restrict__ src,
    const int* __restrict__ dst, const float* __restrict__ dis,
    const int* __restrict__ curb, int2* __restrict__ epk,
    const int* __restrict__ flagpart, int* __restrict__ hflag,
    int E, int n, int ech, int rs, int cvb) {

    __shared__ int curL[RSF_MAX];

    const int b    = blockIdx.x & (NB - 1);
    const int r    = blockIdx.x >> 7;
    const int base = r * rs;
    const int rse  = min(rs, n - base);

    if (blockIdx.x == 0) {
        int fl = 0;
        for (int i = threadIdx.x; i < cvb; i += 512) fl |= flagpart[i];
        unsigned long long m = __ballot(fl != 0);
        if ((threadIdx.x & 63) == 0 && m) atomicOr(hflag, 1);
    }

    const int* crow = curb + (size_t)b * n + base;
    for (int i = threadIdx.x; i < rse; i += 512) curL[i] = crow[i];
    __syncthreads();

    const int e0 = b * ech, e1 = min(e0 + ech, E);
    int e = e0 + (int)threadIdx.x * 2;
    for (; e + 1 < e1; e += 1024) {
        int2   s2 = *reinterpret_cast<const int2*>(src + e);
        int2   d2 = *reinterpret_cast<const int2*>(dst + e);
        float2 w2 = *reinterpret_cast<const float2*>(ew + e);
        unsigned int rd0 = (unsigned int)(d2.x - base);
        if (rd0 < (unsigned int)rse) {
            float w = -dis[s2.x] * w2.x * dis[d2.x];
            int p = atomicAdd(&curL[rd0], 1);
            epk[p] = make_int2(s2.x, __builtin_bit_cast(int, w));
        }
        unsigned int rd1 = (unsigned int)(d2.y - base);
        if (rd1 < (unsigned int)rse) {
            float w = -dis[s2.y] * w2.y * dis[d2.y];
            int p = atomicAdd(&curL[rd1], 1);
            epk[p] = make_int2(s2.y, __builtin_bit_cast(int, w));
        }
    }
    if (e < e1) {
        int d = dst[e];
        unsigned int rd_ = (unsigned int)(d - base);
        if (rd_ < (unsigned int)rse) {
            int s = src[e];
            float w = -dis[s] * ew[e] * dis[d];
            int p = atomicAdd(&curL[rd_], 1);
            epk[p] = make_int2(s, __builtin_bit_cast(int, w));
        }
    }
}

// ---- Kernel 4: gather -> writes tx/th ROWS (coalesced 256B per wave) ----
__global__ __launch_bounds__(256) void k_gather_bf(
    const unsigned int* __restrict__ xw, const unsigned int* __restrict__ hw,
    const int* __restrict__ off, const int* __restrict__ cntv,
    const int2* __restrict__ epk, const int* __restrict__ hflag,
    unsigned int* __restrict__ txw, unsigned int* __restrict__ thw, int n) {

    int d    = blockIdx.x * 4 + (threadIdx.x >> 6);
    int lane = threadIdx.x & 63;
    if (d >= n) return;
    const bool hasH = (*hflag) != 0;

    int p0 = off[d], p1 = p0 + cntv[d];
    float ax0 = 0.f, ax1 = 0.f, ah0 = 0.f, ah1 = 0.f;

    if (!hasH) {
        for (int base = p0; base < p1; base += 64) {
            int cnt = min(64, p1 - base);
            int2 my = make_int2(0, 0);
            if (lane < cnt) my = epk[base + lane];
            int   sm = my.x;
            float wm = __builtin_bit_cast(float, my.y);
            int k = 0;
            for (; k + 4 <= cnt; k += 4) {
                int   s0 = __shfl(sm, k),     s1 = __shfl(sm, k + 1);
                int   s2 = __shfl(sm, k + 2), s3 = __shfl(sm, k + 3);
                float w0 = __shfl(wm, k),     w1 = __shfl(wm, k + 1);
                float w2 = __shfl(wm, k + 2), w3 = __shfl(wm, k + 3);
                unsigned int u0 = xw[s0 * 64 + lane];
                unsigned int u1 = xw[s1 * 64 + lane];
                unsigned int u2 = xw[s2 * 64 + lane];
                unsigned int u3 = xw[s3 * 64 + lane];
                ax0 = fmaf(w0, bflo(u0), ax0); ax1 = fmaf(w0, bfhi(u0), ax1);
                ax0 = fmaf(w1, bflo(u1), ax0); ax1 = fmaf(w1, bfhi(u1), ax1);
                ax0 = fmaf(w2, bflo(u2), ax0); ax1 = fmaf(w2, bfhi(u2), ax1);
                ax0 = fmaf(w3, bflo(u3), ax0); ax1 = fmaf(w3, bfhi(u3), ax1);
            }
            for (; k < cnt; ++k) {
                int s = __shfl(sm, k);
                float w = __shfl(wm, k);
                unsigned int u = xw[s * 64 + lane];
                ax0 = fmaf(w, bflo(u), ax0); ax1 = fmaf(w, bfhi(u), ax1);
            }
        }
        txw[(size_t)d * 64 + lane] = pack2bf(ax0, ax1);
    } else {
        for (int base = p0; base < p1; base += 64) {
            int cnt = min(64, p1 - base);
            int2 my = make_int2(0, 0);
            if (lane < cnt) my = epk[base + lane];
            int   sm = my.x;
            float wm = __builtin_bit_cast(float, my.y);
            int k = 0;
            for (; k + 2 <= cnt; k += 2) {
                int   s0 = __shfl(sm, k), s1 = __shfl(sm, k + 1);
                float w0 = __shfl(wm, k), w1 = __shfl(wm, k + 1);
                unsigned int u0 = xw[s0 * 64 + lane];
                unsigned int v0 = hw[s0 * 64 + lane];
                unsigned int u1 = xw[s1 * 64 + lane];
                unsigned int v1 = hw[s1 * 64 + lane];
                ax0 = fmaf(w0, bflo(u0), ax0); ax1 = fmaf(w0, bfhi(u0), ax1);
                ah0 = fmaf(w0, bflo(v0), ah0); ah1 = fmaf(w0, bfhi(v0), ah1);
                ax0 = fmaf(w1, bflo(u1), ax0); ax1 = fmaf(w1, bfhi(u1), ax1);
                ah0 = fmaf(w1, bflo(v1), ah0); ah1 = fmaf(w1, bfhi(v1), ah1);
            }
            for (; k < cnt; ++k) {
                int s = __shfl(sm, k);
                float w = __shfl(wm, k);
                unsigned int u = xw[s * 64 + lane];
                unsigned int v = hw[s * 64 + lane];
                ax0 = fmaf(w, bflo(u), ax0); ax1 = fmaf(w, bfhi(u), ax1);
                ah0 = fmaf(w, bflo(v), ah0); ah1 = fmaf(w, bfhi(v), ah1);
            }
        }
        txw[(size_t)d * 64 + lane] = pack2bf(ax0, ax1);
        thw[(size_t)d * 64 + lane] = pack2bf(ah0, ah1);
    }
}

// ---- Kernel 5: GEMM+LSTM; 32-row tiles (proven best) + c/bias prefetch ----
// Block = 32-row tile, 8 waves (626 blocks). ldsR = raw rows (x then h),
// ldsG = gathered (tx then th).
// A-frag (mi,kb): uint4 at lds[mi*16+(lane&15)][(kb&3)*16+(lane>>4)*4], mi 0..1
__global__ __launch_bounds__(512) void k_gemm_lstm(
    const unsigned int* __restrict__ xw, const unsigned int* __restrict__ txw,
    const unsigned int* __restrict__ hw, const unsigned int* __restrict__ thw,
    const unsigned short* __restrict__ Wbf, const int* __restrict__ hflag,
    const float* __restrict__ c, const float* __restrict__ bias,
    const float* __restrict__ wc, float* __restrict__ out, int n) {

    __shared__ unsigned int ldsR[32][LDW];
    __shared__ unsigned int ldsG[32][LDW];

    const int rt   = blockIdx.x;
    const int tid  = threadIdx.x;
    const int jj   = tid >> 6;
    const int lane = tid & 63;
    const int r0   = rt * 32;
    const bool hasH = (*hflag) != 0;

    const int col = jj * 16 + (lane & 15);

    // early: prefetch epilogue operands (hide HBM latency under MFMA phase)
    const float wc0 = wc[0 * FD + col], wc1 = wc[1 * FD + col], wc2 = wc[2 * FD + col];
    const float b0  = bias[0 * FD + col], b1 = bias[1 * FD + col];
    const float b2  = bias[2 * FD + col], b3 = bias[3 * FD + col];
    float cv[2][4];
    #pragma unroll
    for (int mi = 0; mi < 2; ++mi)
        #pragma unroll
        for (int q = 0; q < 4; ++q) {
            int r = r0 + mi * 16 + (lane >> 4) * 4 + q;
            cv[mi][q] = (r < n) ? c[(size_t)r * FD + col] : 0.f;
        }

    f32x4 acc[2][4];
    #pragma unroll
    for (int mi = 0; mi < 2; ++mi)
        #pragma unroll
        for (int g = 0; g < 4; ++g)
            acc[mi][g] = (f32x4)0.0f;

    // stage x + tx rows (32 rows x 64 uints each; thread: 1 uint4 per array)
    {
        int sr = tid >> 4, sc = (tid & 15) * 4;
        uint4 v = make_uint4(0,0,0,0), g = make_uint4(0,0,0,0);
        if (r0 + sr < n) {
            v = *reinterpret_cast<const uint4*>(xw  + (size_t)(r0 + sr) * 64 + sc);
            g = *reinterpret_cast<const uint4*>(txw + (size_t)(r0 + sr) * 64 + sc);
        }
        *reinterpret_cast<uint4*>(&ldsR[sr][sc]) = v;
        *reinterpret_cast<uint4*>(&ldsG[sr][sc]) = g;
    }
    __syncthreads();

    #pragma unroll
    for (int kb = 0; kb < 8; ++kb) {
        bf16x8 a[2], b[4];
        const int c0 = (kb & 3) * 16 + (lane >> 4) * 4;
        #pragma unroll
        for (int mi = 0; mi < 2; ++mi) {
            const unsigned int* lp = (kb < 4) ? &ldsR[mi * 16 + (lane & 15)][c0]
                                              : &ldsG[mi * 16 + (lane & 15)][c0];
            a[mi] = __builtin_bit_cast(bf16x8, *reinterpret_cast<const uint4*>(lp));
        }
        #pragma unroll
        for (int g = 0; g < 4; ++g)
            b[g] = *reinterpret_cast<const bf16x8*>(
                Wbf + ((size_t)(g * 8 + jj) * 16 + kb) * 512 + lane * 8);
        #pragma unroll
        for (int mi = 0; mi < 2; ++mi)
            #pragma unroll
            for (int g = 0; g < 4; ++g)
                acc[mi][g] = __builtin_amdgcn_mfma_f32_16x16x32_bf16(
                                 a[mi], b[g], acc[mi][g], 0, 0, 0);
    }

    if (hasH) {
        __syncthreads();
        {
            int sr = tid >> 4, sc = (tid & 15) * 4;
            uint4 v = make_uint4(0,0,0,0), g = make_uint4(0,0,0,0);
            if (r0 + sr < n) {
                v = *reinterpret_cast<const uint4*>(hw  + (size_t)(r0 + sr) * 64 + sc);
                g = *reinterpret_cast<const uint4*>(thw + (size_t)(r0 + sr) * 64 + sc);
            }
            *reinterpret_cast<uint4*>(&ldsR[sr][sc]) = v;
            *reinterpret_cast<uint4*>(&ldsG[sr][sc]) = g;
        }
        __syncthreads();

        #pragma unroll
        for (int kk = 0; kk < 8; ++kk) {
            const int kb = 8 + kk;
            bf16x8 a[2], b[4];
            const int c0 = (kk & 3) * 16 + (lane >> 4) * 4;
            #pragma unroll
            for (int mi = 0; mi < 2; ++mi) {
                const unsigned int* lp = (kk < 4) ? &ldsR[mi * 16 + (lane & 15)][c0]
                                                  : &ldsG[mi * 16 + (lane & 15)][c0];
                a[mi] = __builtin_bit_cast(bf16x8, *reinterpret_cast<const uint4*>(lp));
            }
            #pragma unroll
            for (int g = 0; g < 4; ++g)
                b[g] = *reinterpret_cast<const bf16x8*>(
                    Wbf + ((size_t)(g * 8 + jj) * 16 + kb) * 512 + lane * 8);
            #pragma unroll
            for (int mi = 0; mi < 2; ++mi)
                #pragma unroll
                for (int g = 0; g < 4; ++g)
                    acc[mi][g] = __builtin_amdgcn_mfma_f32_16x16x32_bf16(
                                     a[mi], b[g], acc[mi][g], 0, 0, 0);
        }
    }

    const size_t NH = (size_t)n * FD;
    #pragma unroll
    for (int mi = 0; mi < 2; ++mi) {
        #pragma unroll
        for (int q = 0; q < 4; ++q) {
            int r = r0 + mi * 16 + (lane >> 4) * 4 + q;
            if (r >= n) continue;
            float cvv = cv[mi][q];
            float gi = acc[mi][0][q] + wc0 * cvv + b0;
            float gf = acc[mi][1][q] + wc1 * cvv + b1;
            float gg = acc[mi][2][q] + b2;
            float iv = sigmoidf_(gi);
            float fv = sigmoidf_(gf);
            float cn = fv * cvv + iv * tanhf(gg);
            float go = acc[mi][3][q] + wc2 * cn + b3;
            float hn = sigmoidf_(go) * tanhf(cn);
            size_t o = (size_t)r * FD + col;
            out[o]          = hn;
            out[NH + o]     = hn;
            out[2 * NH + o] = cn;
        }
    }
}

extern "C" void kernel_launch(void* const* d_in, const int* in_sizes, int n_in,
                              void* d_out, int out_size, void* d_ws, size_t ws_size,
                              hipStream_t stream) {
    const float* x   = (const float*)d_in[0];
    const float* ew  = (const float*)d_in[1];
    const float* h   = (const float*)d_in[2];
    const float* c   = (const float*)d_in[3];
    const float* Wx  = (const float*)d_in[4];
    const float* Wh  = (const float*)d_in[5];
    const float* b   = (const float*)d_in[6];
    const float* wc  = (const float*)d_in[7];
    const int*   src = (const int*)d_in[8];
    const int*   dst = (const int*)d_in[9];

    const int n = in_sizes[0] / FD;   // 20000  (<= NMAX)
    const int E = in_sizes[1];        // 640000

    const int Mpad = (n + 31) & ~31;              // 32-row tiles
    const int ech  = (E + NB - 1) / NB;           // 5000
    const int rsh  = (n + NRH - 1) / NRH;         // 10000
    const int rsf  = (n + NRF - 1) / NRF;         // 10000
    const int n16  = n * 16;
    const int cvb  = (n16 + 511) / 512;           // cvt section blocks
    const int npf  = (n + 127) / 128;             // fold blocks

    // ---- workspace layout ----
    float* dis      = (float*)d_ws;                        // n
    int*   cnt      = (int*)(dis + n);                     // n
    int*   off      = cnt + n;                             // n+4
    int*   hflag    = off + n + 4;                         // 4
    int*   cursor   = hflag + 4;                           // 4
    int*   flagpart = cursor + 4;                          // 1280 (pad)
    int2*  epk      = (int2*)(flagpart + 1280);            // E
    unsigned int* xw  = (unsigned int*)(epk + E);          // n*64
    unsigned int* hw  = xw + (size_t)n * 64;               // n*64
    unsigned int* txw = hw + (size_t)n * 64;               // n*64
    unsigned int* thw = txw + (size_t)n * 64;              // n*64
    unsigned short* Wbf = (unsigned short*)(thw + (size_t)n * 64); // 512*512
    int*   curb     = (int*)(Wbf + 512 * 512);             // NB*n
    float* deg_priv = (float*)(curb + (size_t)NB * n);     // NB*n
    unsigned short* cnt_priv = (unsigned short*)(deg_priv + (size_t)NB * n); // NB*n

    k_front<<<NB * NRH + cvb + 64, 512, 0, stream>>>(
        ew, src, dst, deg_priv, cnt_priv, cursor, hflag,
        x, h, Wx, Wh, xw, hw, Wbf, flagpart,
        E, n, ech, rsh, n16, cvb);
    k_fold<<<npf, 512, 0, stream>>>(deg_priv, cnt_priv, dis, cnt, off, curb,
                                    cursor, n);
    k_fill_lds<<<NB * NRF, 512, 0, stream>>>(ew, src, dst, dis, curb, epk,
                                             flagpart, hflag, E, n, ech, rsf, cvb);
    k_gather_bf<<<(n + 3) / 4, 256, 0, stream>>>(xw, hw, off, cnt, epk, hflag,
                                                 txw, thw, n);
    k_gemm_lstm<<<Mpad / 32, 512, 0, stream>>>(xw, txw, hw, thw, Wbf, hflag,
                                               c, b, wc, (float*)d_out, n);
}

// Round 22
// 81.678 us; speedup vs baseline: 1.0730x; 1.0391x over previous
//
#include <hip/hip_runtime.h>
#include <math.h>

#define FD 128
#define GATES 4
#define NB   128           // edge chunks (per-chunk private histograms)
#define NRH  2             // hist node ranges
#define NRF  2             // fill node ranges
#define RSH_MAX 10016
#define RSF_MAX 10016
#define NMAX (RSH_MAX * 2)
#define LDW 68             // LDS tile row stride in uints (64 + 4 pad)

typedef __attribute__((ext_vector_type(8))) short bf16x8;
typedef __attribute__((ext_vector_type(4))) float f32x4;

// fast sigmoid/tanh via v_exp_f32 (safe at +-inf)
__device__ __forceinline__ float fsig(float v) {
    return 1.0f / (1.0f + __expf(-v));
}
__device__ __forceinline__ float ftanh(float v) {
    return 1.0f - 2.0f / (__expf(2.0f * v) + 1.0f);
}

__device__ __forceinline__ unsigned short f2bf(float f) {
    unsigned int u = __builtin_bit_cast(unsigned int, f);
    u += 0x7fffu + ((u >> 16) & 1u);           // RNE (finite values)
    return (unsigned short)(u >> 16);
}
__device__ __forceinline__ float bflo(unsigned int u) {
    return __builtin_bit_cast(float, u << 16);
}
__device__ __forceinline__ float bfhi(unsigned int u) {
    return __builtin_bit_cast(float, u & 0xffff0000u);
}
__device__ __forceinline__ unsigned int pack2bf(float lo, float hi) {
    return (unsigned int)f2bf(lo) | ((unsigned int)f2bf(hi) << 16);
}

// ---- Kernel 1: hist (NB*NRH blocks) || cvt (cvb blocks) || pack_w (64) ----
__global__ __launch_bounds__(512) void k_front(
    const float* __restrict__ ew, const int* __restrict__ src,
    const int* __restrict__ dst,
    float* __restrict__ deg_priv, unsigned short* __restrict__ cnt_priv,
    int* __restrict__ cursor, int* __restrict__ hflag,
    const float* __restrict__ x, const float* __restrict__ h,
    const float* __restrict__ Wx, const float* __restrict__ Wh,
    unsigned int* __restrict__ xw, unsigned int* __restrict__ hw,
    unsigned short* __restrict__ Wbf, int* __restrict__ flagpart,
    int E, int n, int ech, int rs, int n16, int cvb) {

    __shared__ float        degL[RSH_MAX];
    __shared__ unsigned int cntP[RSH_MAX / 2];

    const int bid  = blockIdx.x;
    const int tid  = threadIdx.x;
    const int lane = tid & 63;
    const int NH_BLOCKS = NB * NRH;

    if (bid < NH_BLOCKS) {
        // ---------------- hist section (2 edges / thread-iter) ----------------
        if (bid == 0 && tid == 0) { cursor[0] = 0; hflag[0] = 0; }

        const int b    = bid & (NB - 1);
        const int r    = bid >> 7;            // NB==128
        const int base = r * rs;
        const int rse  = min(rs, n - base);
        const int nh   = (rse + 1) >> 1;

        for (int i = tid; i < rse; i += 512) degL[i] = 0.f;
        for (int i = tid; i < nh;  i += 512) cntP[i] = 0u;
        __syncthreads();

        const int e0 = b * ech, e1 = min(e0 + ech, E);
        int e = e0 + tid * 2;
        for (; e + 1 < e1; e += 1024) {
            int2   s2 = *reinterpret_cast<const int2*>(src + e);
            int2   d2 = *reinterpret_cast<const int2*>(dst + e);
            float2 w2 = *reinterpret_cast<const float2*>(ew + e);
            unsigned int rs0 = (unsigned int)(s2.x - base);
            unsigned int rd0 = (unsigned int)(d2.x - base);
            unsigned int rs1 = (unsigned int)(s2.y - base);
            unsigned int rd1 = (unsigned int)(d2.y - base);
            if (rs0 < (unsigned int)rse) atomicAdd(&degL[rs0], w2.x);
            if (rd0 < (unsigned int)rse) atomicAdd(&cntP[rd0 >> 1], (rd0 & 1) ? 0x10000u : 1u);
            if (rs1 < (unsigned int)rse) atomicAdd(&degL[rs1], w2.y);
            if (rd1 < (unsigned int)rse) atomicAdd(&cntP[rd1 >> 1], (rd1 & 1) ? 0x10000u : 1u);
        }
        if (e < e1) {
            int s = src[e], d = dst[e];
            unsigned int rs_ = (unsigned int)(s - base);
            unsigned int rd_ = (unsigned int)(d - base);
            if (rs_ < (unsigned int)rse) atomicAdd(&degL[rs_], ew[e]);
            if (rd_ < (unsigned int)rse) atomicAdd(&cntP[rd_ >> 1], (rd_ & 1) ? 0x10000u : 1u);
        }
        __syncthreads();

        float*          dp = deg_priv + (size_t)b * n + base;
        unsigned short* cp = cnt_priv + (size_t)b * n + base;
        for (int i = tid; i < rse; i += 512) dp[i] = degL[i];
        for (int i = tid; i < rse; i += 512) {
            unsigned int v = cntP[i >> 1];
            cp[i] = (unsigned short)((i & 1) ? (v >> 16) : (v & 0xffffu));
        }
        return;
    }

    if (bid < NH_BLOCKS + cvb) {
        // ---------------- cvt section (rows only) ----------------
        int t = (bid - NH_BLOCKS) * 512 + tid;
        bool nz = false;
        if (t < n16) {
            const float4* xp = reinterpret_cast<const float4*>(x) + (size_t)t * 2;
            float4 a = xp[0], bq = xp[1];
            uint4 ox;
            ox.x = pack2bf(a.x, a.y);   ox.y = pack2bf(a.z, a.w);
            ox.z = pack2bf(bq.x, bq.y); ox.w = pack2bf(bq.z, bq.w);
            reinterpret_cast<uint4*>(xw)[t] = ox;

            const float4* hp = reinterpret_cast<const float4*>(h) + (size_t)t * 2;
            float4 hc = hp[0], hd = hp[1];
            nz = (hc.x != 0.f) | (hc.y != 0.f) | (hc.z != 0.f) | (hc.w != 0.f) |
                 (hd.x != 0.f) | (hd.y != 0.f) | (hd.z != 0.f) | (hd.w != 0.f);
            uint4 oh;
            oh.x = pack2bf(hc.x, hc.y); oh.y = pack2bf(hc.z, hc.w);
            oh.z = pack2bf(hd.x, hd.y); oh.w = pack2bf(hd.z, hd.w);
            reinterpret_cast<uint4*>(hw)[t] = oh;
        }
        __shared__ int fsh;
        if (tid == 0) fsh = 0;
        __syncthreads();
        unsigned long long m = __ballot(nz);
        if (lane == 0 && m) atomicOr(&fsh, 1);
        __syncthreads();
        if (tid == 0) flagpart[bid - NH_BLOCKS] = fsh;
        return;
    }

    // ---------------- pack_w section ----------------
    {
        int frag = (bid - NH_BLOCKS - cvb) * 8 + (tid >> 6);   // 0..511
        int cb = frag >> 4, kb = frag & 15;
        int col = cb * 16 + (lane & 15);
        int k0  = kb * 32 + (lane >> 4) * 8;

        int sel  = k0 >> 7;                // 0..3 : Wx0, Wx1, Wh0, Wh1
        int g    = col >> 7;
        int j    = col & (FD - 1);
        const float* Wb = (sel < 2) ? Wx : Wh;
        const float* p = Wb + (((size_t)g * 2 + (sel & 1)) * FD + (k0 & (FD - 1))) * FD + j;

        unsigned short outv[8];
        #pragma unroll
        for (int i = 0; i < 8; ++i) outv[i] = f2bf(p[(size_t)i * FD]);
        *reinterpret_cast<uint4*>(Wbf + (size_t)frag * 512 + lane * 8) =
            *reinterpret_cast<uint4*>(outv);
    }
}

// ---- Kernel 2: parallel fold (128 d's x 4 chunk-segments per block) ----
__global__ __launch_bounds__(512) void k_fold(
    const float* __restrict__ deg_priv, const unsigned short* __restrict__ cnt_priv,
    float* __restrict__ dis, int* __restrict__ cnt, int* __restrict__ off,
    int* __restrict__ curb, int* __restrict__ cursor, int n) {

    __shared__ float degp[4][128];
    __shared__ int   ctp[4][128];
    __shared__ int   offL[128];

    const int tid = threadIdx.x;
    const int seg = tid >> 7;          // 0..3 (32 chunks each)
    const int dl  = tid & 127;
    const int d   = blockIdx.x * 128 + dl;
    const int b0  = seg * 32;

    float s = 0.f; int ct = 0;
    if (d < n) {
        #pragma unroll 8
        for (int i = 0; i < 32; ++i) {
            int b = b0 + i;
            s  += deg_priv[(size_t)b * n + d];
            ct += (int)cnt_priv[(size_t)b * n + d];
        }
    }
    degp[seg][dl] = s;
    ctp[seg][dl]  = ct;
    __syncthreads();

    if (seg == 0) {
        int   ctt = 0;
        float st  = 0.f;
        #pragma unroll
        for (int q = 0; q < 4; ++q) { ctt += ctp[q][dl]; st += degp[q][dl]; }

        const int lane = tid & 63;
        int s_incl = (d < n) ? ctt : 0;
        #pragma unroll
        for (int o = 1; o < 64; o <<= 1) {
            int t2 = __shfl_up(s_incl, o);
            if (lane >= o) s_incl += t2;
        }
        int wtotal = __shfl(s_incl, 63);
        int base = 0;
        if (lane == 0) base = atomicAdd(cursor, wtotal);
        base = __shfl(base, 0);

        if (d < n) {
            dis[d] = (st > 0.0f) ? rsqrtf(fmaxf(st, 1e-12f)) : 0.0f;
            cnt[d] = ctt;
            int my0 = base + s_incl - ctt;
            off[d]   = my0;
            offL[dl] = my0;
        }
    }
    __syncthreads();

    if (d < n) {
        int run = offL[dl];
        for (int q = 0; q < seg; ++q) run += ctp[q][dl];
        #pragma unroll 8
        for (int i = 0; i < 32; ++i) {
            int b = b0 + i;
            curb[(size_t)b * n + d] = run;
            run += (int)cnt_priv[(size_t)b * n + d];
        }
    }
}

// ---- Kernel 3: bucket fill (2 edges / thread-iter); block 0: hflag OR ----
__global__ __launch_bounds__(512) void k_fill_lds(
    const float* __restrict__ ew, const int* __restrict__ src,
    const int* __restrict__ dst, const float* __restrict__ dis,
    const int* __restrict__ curb, int2* __restrict__ epk,
    const int* __restrict__ flagpart, int* __restrict__ hflag,
    int E, int n, int ech, int rs, int cvb) {

    __shared__ int curL[RSF_MAX];

    const int b    = blockIdx.x & (NB - 1);
    const int r    = blockIdx.x >> 7;
    const int base = r * rs;
    const int rse  = min(rs, n - base);

    if (blockIdx.x == 0) {
        int fl = 0;
        for (int i = threadIdx.x; i < cvb; i += 512) fl |= flagpart[i];
        unsigned long long m = __ballot(fl != 0);
        if ((threadIdx.x & 63) == 0 && m) atomicOr(hflag, 1);
    }

    const int* crow = curb + (size_t)b * n + base;
    for (int i = threadIdx.x; i < rse; i += 512) curL[i] = crow[i];
    __syncthreads();

    const int e0 = b * ech, e1 = min(e0 + ech, E);
    int e = e0 + (int)threadIdx.x * 2;
    for (; e + 1 < e1; e += 1024) {
        int2   s2 = *reinterpret_cast<const int2*>(src + e);
        int2   d2 = *reinterpret_cast<const int2*>(dst + e);
        float2 w2 = *reinterpret_cast<const float2*>(ew + e);
        unsigned int rd0 = (unsigned int)(d2.x - base);
        if (rd0 < (unsigned int)rse) {
            float w = -dis[s2.x] * w2.x * dis[d2.x];
            int p = atomicAdd(&curL[rd0], 1);
            epk[p] = make_int2(s2.x, __builtin_bit_cast(int, w));
        }
        unsigned int rd1 = (unsigned int)(d2.y - base);
        if (rd1 < (unsigned int)rse) {
            float w = -dis[s2.y] * w2.y * dis[d2.y];
            int p = atomicAdd(&curL[rd1], 1);
            epk[p] = make_int2(s2.y, __builtin_bit_cast(int, w));
        }
    }
    if (e < e1) {
        int d = dst[e];
        unsigned int rd_ = (unsigned int)(d - base);
        if (rd_ < (unsigned int)rse) {
            int s = src[e];
            float w = -dis[s] * ew[e] * dis[d];
            int p = atomicAdd(&curL[rd_], 1);
            epk[p] = make_int2(s, __builtin_bit_cast(int, w));
        }
    }
}

// ---- Kernel 4: gather -> tx/th ROWS; unroll-8 for deeper MLP ----
__global__ __launch_bounds__(256) void k_gather_bf(
    const unsigned int* __restrict__ xw, const unsigned int* __restrict__ hw,
    const int* __restrict__ off, const int* __restrict__ cntv,
    const int2* __restrict__ epk, const int* __restrict__ hflag,
    unsigned int* __restrict__ txw, unsigned int* __restrict__ thw, int n) {

    int d    = blockIdx.x * 4 + (threadIdx.x >> 6);
    int lane = threadIdx.x & 63;
    if (d >= n) return;
    const bool hasH = (*hflag) != 0;

    int p0 = off[d], p1 = p0 + cntv[d];
    float ax0 = 0.f, ax1 = 0.f, ah0 = 0.f, ah1 = 0.f;

    if (!hasH) {
        for (int base = p0; base < p1; base += 64) {
            int cnt = min(64, p1 - base);
            int2 my = make_int2(0, 0);
            if (lane < cnt) my = epk[base + lane];
            int   sm = my.x;
            float wm = __builtin_bit_cast(float, my.y);
            int k = 0;
            for (; k + 8 <= cnt; k += 8) {
                int   s0 = __shfl(sm, k),     s1 = __shfl(sm, k + 1);
                int   s2 = __shfl(sm, k + 2), s3 = __shfl(sm, k + 3);
                int   s4 = __shfl(sm, k + 4), s5 = __shfl(sm, k + 5);
                int   s6 = __shfl(sm, k + 6), s7 = __shfl(sm, k + 7);
                float w0 = __shfl(wm, k),     w1 = __shfl(wm, k + 1);
                float w2 = __shfl(wm, k + 2), w3 = __shfl(wm, k + 3);
                float w4 = __shfl(wm, k + 4), w5 = __shfl(wm, k + 5);
                float w6 = __shfl(wm, k + 6), w7 = __shfl(wm, k + 7);
                unsigned int u0 = xw[s0 * 64 + lane];
                unsigned int u1 = xw[s1 * 64 + lane];
                unsigned int u2 = xw[s2 * 64 + lane];
                unsigned int u3 = xw[s3 * 64 + lane];
                unsigned int u4 = xw[s4 * 64 + lane];
                unsigned int u5 = xw[s5 * 64 + lane];
                unsigned int u6 = xw[s6 * 64 + lane];
                unsigned int u7 = xw[s7 * 64 + lane];
                ax0 = fmaf(w0, bflo(u0), ax0); ax1 = fmaf(w0, bfhi(u0), ax1);
                ax0 = fmaf(w1, bflo(u1), ax0); ax1 = fmaf(w1, bfhi(u1), ax1);
                ax0 = fmaf(w2, bflo(u2), ax0); ax1 = fmaf(w2, bfhi(u2), ax1);
                ax0 = fmaf(w3, bflo(u3), ax0); ax1 = fmaf(w3, bfhi(u3), ax1);
                ax0 = fmaf(w4, bflo(u4), ax0); ax1 = fmaf(w4, bfhi(u4), ax1);
                ax0 = fmaf(w5, bflo(u5), ax0); ax1 = fmaf(w5, bfhi(u5), ax1);
                ax0 = fmaf(w6, bflo(u6), ax0); ax1 = fmaf(w6, bfhi(u6), ax1);
                ax0 = fmaf(w7, bflo(u7), ax0); ax1 = fmaf(w7, bfhi(u7), ax1);
            }
            for (; k < cnt; ++k) {
                int s = __shfl(sm, k);
                float w = __shfl(wm, k);
                unsigned int u = xw[s * 64 + lane];
                ax0 = fmaf(w, bflo(u), ax0); ax1 = fmaf(w, bfhi(u), ax1);
            }
        }
        txw[(size_t)d * 64 + lane] = pack2bf(ax0, ax1);
    } else {
        for (int base = p0; base < p1; base += 64) {
            int cnt = min(64, p1 - base);
            int2 my = make_int2(0, 0);
            if (lane < cnt) my = epk[base + lane];
            int   sm = my.x;
            float wm = __builtin_bit_cast(float, my.y);
            int k = 0;
            for (; k + 4 <= cnt; k += 4) {
                int   s0 = __shfl(sm, k), s1 = __shfl(sm, k + 1);
                int   s2 = __shfl(sm, k + 2), s3 = __shfl(sm, k + 3);
                float w0 = __shfl(wm, k), w1 = __shfl(wm, k + 1);
                float w2 = __shfl(wm, k + 2), w3 = __shfl(wm, k + 3);
                unsigned int u0 = xw[s0 * 64 + lane];
                unsigned int v0 = hw[s0 * 64 + lane];
                unsigned int u1 = xw[s1 * 64 + lane];
                unsigned int v1 = hw[s1 * 64 + lane];
                unsigned int u2 = xw[s2 * 64 + lane];
                unsigned int v2 = hw[s2 * 64 + lane];
                unsigned int u3 = xw[s3 * 64 + lane];
                unsigned int v3 = hw[s3 * 64 + lane];
                ax0 = fmaf(w0, bflo(u0), ax0); ax1 = fmaf(w0, bfhi(u0), ax1);
                ah0 = fmaf(w0, bflo(v0), ah0); ah1 = fmaf(w0, bfhi(v0), ah1);
                ax0 = fmaf(w1, bflo(u1), ax0); ax1 = fmaf(w1, bfhi(u1), ax1);
                ah0 = fmaf(w1, bflo(v1), ah0); ah1 = fmaf(w1, bfhi(v1), ah1);
                ax0 = fmaf(w2, bflo(u2), ax0); ax1 = fmaf(w2, bfhi(u2), ax1);
                ah0 = fmaf(w2, bflo(v2), ah0); ah1 = fmaf(w2, bfhi(v2), ah1);
                ax0 = fmaf(w3, bflo(u3), ax0); ax1 = fmaf(w3, bfhi(u3), ax1);
                ah0 = fmaf(w3, bflo(v3), ah0); ah1 = fmaf(w3, bfhi(v3), ah1);
            }
            for (; k < cnt; ++k) {
                int s = __shfl(sm, k);
                float w = __shfl(wm, k);
                unsigned int u = xw[s * 64 + lane];
                unsigned int v = hw[s * 64 + lane];
                ax0 = fmaf(w, bflo(u), ax0); ax1 = fmaf(w, bfhi(u), ax1);
                ah0 = fmaf(w, bflo(v), ah0); ah1 = fmaf(w, bfhi(v), ah1);
            }
        }
        txw[(size_t)d * 64 + lane] = pack2bf(ax0, ax1);
        thw[(size_t)d * 64 + lane] = pack2bf(ah0, ah1);
    }
}

// ---- Kernel 5: GEMM+LSTM; 32-row tiles + prefetch + native-exp epilogue ----
__global__ __launch_bounds__(512) void k_gemm_lstm(
    const unsigned int* __restrict__ xw, const unsigned int* __restrict__ txw,
    const unsigned int* __restrict__ hw, const unsigned int* __restrict__ thw,
    const unsigned short* __restrict__ Wbf, const int* __restrict__ hflag,
    const float* __restrict__ c, const float* __restrict__ bias,
    const float* __restrict__ wc, float* __restrict__ out, int n) {

    __shared__ unsigned int ldsR[32][LDW];
    __shared__ unsigned int ldsG[32][LDW];

    const int rt   = blockIdx.x;
    const int tid  = threadIdx.x;
    const int jj   = tid >> 6;
    const int lane = tid & 63;
    const int r0   = rt * 32;
    const bool hasH = (*hflag) != 0;

    const int col = jj * 16 + (lane & 15);

    // early: prefetch epilogue operands (hide latency under MFMA phase)
    const float wc0 = wc[0 * FD + col], wc1 = wc[1 * FD + col], wc2 = wc[2 * FD + col];
    const float b0  = bias[0 * FD + col], b1 = bias[1 * FD + col];
    const float b2  = bias[2 * FD + col], b3 = bias[3 * FD + col];
    float cv[2][4];
    #pragma unroll
    for (int mi = 0; mi < 2; ++mi)
        #pragma unroll
        for (int q = 0; q < 4; ++q) {
            int r = r0 + mi * 16 + (lane >> 4) * 4 + q;
            cv[mi][q] = (r < n) ? c[(size_t)r * FD + col] : 0.f;
        }

    f32x4 acc[2][4];
    #pragma unroll
    for (int mi = 0; mi < 2; ++mi)
        #pragma unroll
        for (int g = 0; g < 4; ++g)
            acc[mi][g] = (f32x4)0.0f;

    // stage x + tx rows
    {
        int sr = tid >> 4, sc = (tid & 15) * 4;
        uint4 v = make_uint4(0,0,0,0), g = make_uint4(0,0,0,0);
        if (r0 + sr < n) {
            v = *reinterpret_cast<const uint4*>(xw  + (size_t)(r0 + sr) * 64 + sc);
            g = *reinterpret_cast<const uint4*>(txw + (size_t)(r0 + sr) * 64 + sc);
        }
        *reinterpret_cast<uint4*>(&ldsR[sr][sc]) = v;
        *reinterpret_cast<uint4*>(&ldsG[sr][sc]) = g;
    }
    __syncthreads();

    #pragma unroll
    for (int kb = 0; kb < 8; ++kb) {
        bf16x8 a[2], b[4];
        const int c0 = (kb & 3) * 16 + (lane >> 4) * 4;
        #pragma unroll
        for (int mi = 0; mi < 2; ++mi) {
            const unsigned int* lp = (kb < 4) ? &ldsR[mi * 16 + (lane & 15)][c0]
                                              : &ldsG[mi * 16 + (lane & 15)][c0];
            a[mi] = __builtin_bit_cast(bf16x8, *reinterpret_cast<const uint4*>(lp));
        }
        #pragma unroll
        for (int g = 0; g < 4; ++g)
            b[g] = *reinterpret_cast<const bf16x8*>(
                Wbf + ((size_t)(g * 8 + jj) * 16 + kb) * 512 + lane * 8);
        #pragma unroll
        for (int mi = 0; mi < 2; ++mi)
            #pragma unroll
            for (int g = 0; g < 4; ++g)
                acc[mi][g] = __builtin_amdgcn_mfma_f32_16x16x32_bf16(
                                 a[mi], b[g], acc[mi][g], 0, 0, 0);
    }

    if (hasH) {
        __syncthreads();
        {
            int sr = tid >> 4, sc = (tid & 15) * 4;
            uint4 v = make_uint4(0,0,0,0), g = make_uint4(0,0,0,0);
            if (r0 + sr < n) {
                v = *reinterpret_cast<const uint4*>(hw  + (size_t)(r0 + sr) * 64 + sc);
                g = *reinterpret_cast<const uint4*>(thw + (size_t)(r0 + sr) * 64 + sc);
            }
            *reinterpret_cast<uint4*>(&ldsR[sr][sc]) = v;
            *reinterpret_cast<uint4*>(&ldsG[sr][sc]) = g;
        }
        __syncthreads();

        #pragma unroll
        for (int kk = 0; kk < 8; ++kk) {
            const int kb = 8 + kk;
            bf16x8 a[2], b[4];
            const int c0 = (kk & 3) * 16 + (lane >> 4) * 4;
            #pragma unroll
            for (int mi = 0; mi < 2; ++mi) {
                const unsigned int* lp = (kk < 4) ? &ldsR[mi * 16 + (lane & 15)][c0]
                                                  : &ldsG[mi * 16 + (lane & 15)][c0];
                a[mi] = __builtin_bit_cast(bf16x8, *reinterpret_cast<const uint4*>(lp));
            }
            #pragma unroll
            for (int g = 0; g < 4; ++g)
                b[g] = *reinterpret_cast<const bf16x8*>(
                    Wbf + ((size_t)(g * 8 + jj) * 16 + kb) * 512 + lane * 8);
            #pragma unroll
            for (int mi = 0; mi < 2; ++mi)
                #pragma unroll
                for (int g = 0; g < 4; ++g)
                    acc[mi][g] = __builtin_amdgcn_mfma_f32_16x16x32_bf16(
                                     a[mi], b[g], acc[mi][g], 0, 0, 0);
        }
    }

    const size_t NH = (size_t)n * FD;
    #pragma unroll
    for (int mi = 0; mi < 2; ++mi) {
        #pragma unroll
        for (int q = 0; q < 4; ++q) {
            int r = r0 + mi * 16 + (lane >> 4) * 4 + q;
            if (r >= n) continue;
            float cvv = cv[mi][q];
            float gi = acc[mi][0][q] + wc0 * cvv + b0;
            float gf = acc[mi][1][q] + wc1 * cvv + b1;
            float gg = acc[mi][2][q] + b2;
            float iv = fsig(gi);
            float fv = fsig(gf);
            float cn = fv * cvv + iv * ftanh(gg);
            float go = acc[mi][3][q] + wc2 * cn + b3;
            float hn = fsig(go) * ftanh(cn);
            size_t o = (size_t)r * FD + col;
            out[o]          = hn;
            out[NH + o]     = hn;
            out[2 * NH + o] = cn;
        }
    }
}

extern "C" void kernel_launch(void* const* d_in, const int* in_sizes, int n_in,
                              void* d_out, int out_size, void* d_ws, size_t ws_size,
                              hipStream_t stream) {
    const float* x   = (const float*)d_in[0];
    const float* ew  = (const float*)d_in[1];
    const float* h   = (const float*)d_in[2];
    const float* c   = (const float*)d_in[3];
    const float* Wx  = (const float*)d_in[4];
    const float* Wh  = (const float*)d_in[5];
    const float* b   = (const float*)d_in[6];
    const float* wc  = (const float*)d_in[7];
    const int*   src = (const int*)d_in[8];
    const int*   dst = (const int*)d_in[9];

    const int n = in_sizes[0] / FD;   // 20000  (<= NMAX)
    const int E = in_sizes[1];        // 640000

    const int Mpad = (n + 31) & ~31;              // 32-row tiles
    const int ech  = (E + NB - 1) / NB;           // 5000
    const int rsh  = (n + NRH - 1) / NRH;         // 10000
    const int rsf  = (n + NRF - 1) / NRF;         // 10000
    const int n16  = n * 16;
    const int cvb  = (n16 + 511) / 512;           // cvt section blocks
    const int npf  = (n + 127) / 128;             // fold blocks

    // ---- workspace layout ----
    float* dis      = (float*)d_ws;                        // n
    int*   cnt      = (int*)(dis + n);                     // n
    int*   off      = cnt + n;                             // n+4
    int*   hflag    = off + n + 4;                         // 4
    int*   cursor   = hflag + 4;                           // 4
    int*   flagpart = cursor + 4;                          // 1280 (pad)
    int2*  epk      = (int2*)(flagpart + 1280);            // E
    unsigned int* xw  = (unsigned int*)(epk + E);          // n*64
    unsigned int* hw  = xw + (size_t)n * 64;               // n*64
    unsigned int* txw = hw + (size_t)n * 64;               // n*64
    unsigned int* thw = txw + (size_t)n * 64;              // n*64
    unsigned short* Wbf = (unsigned short*)(thw + (size_t)n * 64); // 512*512
    int*   curb     = (int*)(Wbf + 512 * 512);             // NB*n
    float* deg_priv = (float*)(curb + (size_t)NB * n);     // NB*n
    unsigned short* cnt_priv = (unsigned short*)(deg_priv + (size_t)NB * n); // NB*n

    k_front<<<NB * NRH + cvb + 64, 512, 0, stream>>>(
        ew, src, dst, deg_priv, cnt_priv, cursor, hflag,
        x, h, Wx, Wh, xw, hw, Wbf, flagpart,
        E, n, ech, rsh, n16, cvb);
    k_fold<<<npf, 512, 0, stream>>>(deg_priv, cnt_priv, dis, cnt, off, curb,
                                    cursor, n);
    k_fill_lds<<<NB * NRF, 512, 0, stream>>>(ew, src, dst, dis, curb, epk,
                                             flagpart, hflag, E, n, ech, rsf, cvb);
    k_gather_bf<<<(n + 3) / 4, 256, 0, stream>>>(xw, hw, off, cnt, epk, hflag,
                                                 txw, thw, n);
    k_gemm_lstm<<<Mpad / 32, 512, 0, stream>>>(xw, txw, hw, thw, Wbf, hflag,
                                               c, b, wc, (float*)d_out, n);
}

// Round 23
// 79.665 us; speedup vs baseline: 1.1001x; 1.0253x over previous
//
#include <hip/hip_runtime.h>
#include <math.h>

#define FD 128
#define GATES 4
#define NB   128           // edge chunks (per-chunk private histograms)
#define NRH  2             // hist node ranges
#define NRF  2             // fill node ranges
#define RSH_MAX 10016
#define RSF_MAX 10016
#define NMAX (RSH_MAX * 2)
#define LDW 68             // LDS tile row stride in uints (64 + 4 pad)

typedef __attribute__((ext_vector_type(8))) short bf16x8;
typedef __attribute__((ext_vector_type(4))) float f32x4;

// fast sigmoid/tanh via v_exp_f32 (safe at +-inf)
__device__ __forceinline__ float fsig(float v) {
    return 1.0f / (1.0f + __expf(-v));
}
__device__ __forceinline__ float ftanh(float v) {
    return 1.0f - 2.0f / (__expf(2.0f * v) + 1.0f);
}

__device__ __forceinline__ unsigned short f2bf(float f) {
    unsigned int u = __builtin_bit_cast(unsigned int, f);
    u += 0x7fffu + ((u >> 16) & 1u);           // RNE (finite values)
    return (unsigned short)(u >> 16);
}
__device__ __forceinline__ float bflo(unsigned int u) {
    return __builtin_bit_cast(float, u << 16);
}
__device__ __forceinline__ float bfhi(unsigned int u) {
    return __builtin_bit_cast(float, u & 0xffff0000u);
}
__device__ __forceinline__ unsigned int pack2bf(float lo, float hi) {
    return (unsigned int)f2bf(lo) | ((unsigned int)f2bf(hi) << 16);
}
// edge record: low 16 = src (u16), high 16 = w_sym (bf16)
__device__ __forceinline__ unsigned int packedge(int s, float w) {
    return (unsigned int)s | ((unsigned int)f2bf(w) << 16);
}

// ---- Kernel 1: hist (NB*NRH blocks) || cvt (cvb blocks) || pack_w (64) ----
__global__ __launch_bounds__(512) void k_front(
    const float* __restrict__ ew, const int* __restrict__ src,
    const int* __restrict__ dst,
    float* __restrict__ deg_priv, unsigned short* __restrict__ cnt_priv,
    int* __restrict__ cursor, int* __restrict__ hflag,
    const float* __restrict__ x, const float* __restrict__ h,
    const float* __restrict__ Wx, const float* __restrict__ Wh,
    unsigned int* __restrict__ xw, unsigned int* __restrict__ hw,
    unsigned short* __restrict__ Wbf, int* __restrict__ flagpart,
    int E, int n, int ech, int rs, int n16, int cvb) {

    __shared__ float        degL[RSH_MAX];
    __shared__ unsigned int cntP[RSH_MAX / 2];

    const int bid  = blockIdx.x;
    const int tid  = threadIdx.x;
    const int lane = tid & 63;
    const int NH_BLOCKS = NB * NRH;

    if (bid < NH_BLOCKS) {
        // ---------------- hist section (2 edges / thread-iter) ----------------
        if (bid == 0 && tid == 0) { cursor[0] = 0; hflag[0] = 0; }

        const int b    = bid & (NB - 1);
        const int r    = bid >> 7;            // NB==128
        const int base = r * rs;
        const int rse  = min(rs, n - base);
        const int nh   = (rse + 1) >> 1;

        for (int i = tid; i < rse; i += 512) degL[i] = 0.f;
        for (int i = tid; i < nh;  i += 512) cntP[i] = 0u;
        __syncthreads();

        const int e0 = b * ech, e1 = min(e0 + ech, E);
        int e = e0 + tid * 2;
        for (; e + 1 < e1; e += 1024) {
            int2   s2 = *reinterpret_cast<const int2*>(src + e);
            int2   d2 = *reinterpret_cast<const int2*>(dst + e);
            float2 w2 = *reinterpret_cast<const float2*>(ew + e);
            unsigned int rs0 = (unsigned int)(s2.x - base);
            unsigned int rd0 = (unsigned int)(d2.x - base);
            unsigned int rs1 = (unsigned int)(s2.y - base);
            unsigned int rd1 = (unsigned int)(d2.y - base);
            if (rs0 < (unsigned int)rse) atomicAdd(&degL[rs0], w2.x);
            if (rd0 < (unsigned int)rse) atomicAdd(&cntP[rd0 >> 1], (rd0 & 1) ? 0x10000u : 1u);
            if (rs1 < (unsigned int)rse) atomicAdd(&degL[rs1], w2.y);
            if (rd1 < (unsigned int)rse) atomicAdd(&cntP[rd1 >> 1], (rd1 & 1) ? 0x10000u : 1u);
        }
        if (e < e1) {
            int s = src[e], d = dst[e];
            unsigned int rs_ = (unsigned int)(s - base);
            unsigned int rd_ = (unsigned int)(d - base);
            if (rs_ < (unsigned int)rse) atomicAdd(&degL[rs_], ew[e]);
            if (rd_ < (unsigned int)rse) atomicAdd(&cntP[rd_ >> 1], (rd_ & 1) ? 0x10000u : 1u);
        }
        __syncthreads();

        float*          dp = deg_priv + (size_t)b * n + base;
        unsigned short* cp = cnt_priv + (size_t)b * n + base;
        for (int i = tid; i < rse; i += 512) dp[i] = degL[i];
        for (int i = tid; i < rse; i += 512) {
            unsigned int v = cntP[i >> 1];
            cp[i] = (unsigned short)((i & 1) ? (v >> 16) : (v & 0xffffu));
        }
        return;
    }

    if (bid < NH_BLOCKS + cvb) {
        // ---------------- cvt section (rows only) ----------------
        int t = (bid - NH_BLOCKS) * 512 + tid;
        bool nz = false;
        if (t < n16) {
            const float4* xp = reinterpret_cast<const float4*>(x) + (size_t)t * 2;
            float4 a = xp[0], bq = xp[1];
            uint4 ox;
            ox.x = pack2bf(a.x, a.y);   ox.y = pack2bf(a.z, a.w);
            ox.z = pack2bf(bq.x, bq.y); ox.w = pack2bf(bq.z, bq.w);
            reinterpret_cast<uint4*>(xw)[t] = ox;

            const float4* hp = reinterpret_cast<const float4*>(h) + (size_t)t * 2;
            float4 hc = hp[0], hd = hp[1];
            nz = (hc.x != 0.f) | (hc.y != 0.f) | (hc.z != 0.f) | (hc.w != 0.f) |
                 (hd.x != 0.f) | (hd.y != 0.f) | (hd.z != 0.f) | (hd.w != 0.f);
            uint4 oh;
            oh.x = pack2bf(hc.x, hc.y); oh.y = pack2bf(hc.z, hc.w);
            oh.z = pack2bf(hd.x, hd.y); oh.w = pack2bf(hd.z, hd.w);
            reinterpret_cast<uint4*>(hw)[t] = oh;
        }
        __shared__ int fsh;
        if (tid == 0) fsh = 0;
        __syncthreads();
        unsigned long long m = __ballot(nz);
        if (lane == 0 && m) atomicOr(&fsh, 1);
        __syncthreads();
        if (tid == 0) flagpart[bid - NH_BLOCKS] = fsh;
        return;
    }

    // ---------------- pack_w section ----------------
    {
        int frag = (bid - NH_BLOCKS - cvb) * 8 + (tid >> 6);   // 0..511
        int cb = frag >> 4, kb = frag & 15;
        int col = cb * 16 + (lane & 15);
        int k0  = kb * 32 + (lane >> 4) * 8;

        int sel  = k0 >> 7;                // 0..3 : Wx0, Wx1, Wh0, Wh1
        int g    = col >> 7;
        int j    = col & (FD - 1);
        const float* Wb = (sel < 2) ? Wx : Wh;
        const float* p = Wb + (((size_t)g * 2 + (sel & 1)) * FD + (k0 & (FD - 1))) * FD + j;

        unsigned short outv[8];
        #pragma unroll
        for (int i = 0; i < 8; ++i) outv[i] = f2bf(p[(size_t)i * FD]);
        *reinterpret_cast<uint4*>(Wbf + (size_t)frag * 512 + lane * 8) =
            *reinterpret_cast<uint4*>(outv);
    }
}

// ---- Kernel 2: parallel fold (128 d's x 4 chunk-segments per block) ----
__global__ __launch_bounds__(512) void k_fold(
    const float* __restrict__ deg_priv, const unsigned short* __restrict__ cnt_priv,
    float* __restrict__ dis, int* __restrict__ cnt, int* __restrict__ off,
    int* __restrict__ curb, int* __restrict__ cursor, int n) {

    __shared__ float degp[4][128];
    __shared__ int   ctp[4][128];
    __shared__ int   offL[128];

    const int tid = threadIdx.x;
    const int seg = tid >> 7;          // 0..3 (32 chunks each)
    const int dl  = tid & 127;
    const int d   = blockIdx.x * 128 + dl;
    const int b0  = seg * 32;

    float s = 0.f; int ct = 0;
    if (d < n) {
        #pragma unroll 8
        for (int i = 0; i < 32; ++i) {
            int b = b0 + i;
            s  += deg_priv[(size_t)b * n + d];
            ct += (int)cnt_priv[(size_t)b * n + d];
        }
    }
    degp[seg][dl] = s;
    ctp[seg][dl]  = ct;
    __syncthreads();

    if (seg == 0) {
        int   ctt = 0;
        float st  = 0.f;
        #pragma unroll
        for (int q = 0; q < 4; ++q) { ctt += ctp[q][dl]; st += degp[q][dl]; }

        const int lane = tid & 63;
        int s_incl = (d < n) ? ctt : 0;
        #pragma unroll
        for (int o = 1; o < 64; o <<= 1) {
            int t2 = __shfl_up(s_incl, o);
            if (lane >= o) s_incl += t2;
        }
        int wtotal = __shfl(s_incl, 63);
        int base = 0;
        if (lane == 0) base = atomicAdd(cursor, wtotal);
        base = __shfl(base, 0);

        if (d < n) {
            dis[d] = (st > 0.0f) ? rsqrtf(fmaxf(st, 1e-12f)) : 0.0f;
            cnt[d] = ctt;
            int my0 = base + s_incl - ctt;
            off[d]   = my0;
            offL[dl] = my0;
        }
    }
    __syncthreads();

    if (d < n) {
        int run = offL[dl];
        for (int q = 0; q < seg; ++q) run += ctp[q][dl];
        #pragma unroll 8
        for (int i = 0; i < 32; ++i) {
            int b = b0 + i;
            curb[(size_t)b * n + d] = run;
            run += (int)cnt_priv[(size_t)b * n + d];
        }
    }
}

// ---- Kernel 3: bucket fill (2 edges / thread-iter); packed u16+bf16 epk ----
__global__ __launch_bounds__(512) void k_fill_lds(
    const float* __restrict__ ew, const int* __restrict__ src,
    const int* __restrict__ dst, const float* __restrict__ dis,
    const int* __restrict__ curb, unsigned int* __restrict__ epk,
    const int* __restrict__ flagpart, int* __restrict__ hflag,
    int E, int n, int ech, int rs, int cvb) {

    __shared__ int curL[RSF_MAX];

    const int b    = blockIdx.x & (NB - 1);
    const int r    = blockIdx.x >> 7;
    const int base = r * rs;
    const int rse  = min(rs, n - base);

    if (blockIdx.x == 0) {
        int fl = 0;
        for (int i = threadIdx.x; i < cvb; i += 512) fl |= flagpart[i];
        unsigned long long m = __ballot(fl != 0);
        if ((threadIdx.x & 63) == 0 && m) atomicOr(hflag, 1);
    }

    const int* crow = curb + (size_t)b * n + base;
    for (int i = threadIdx.x; i < rse; i += 512) curL[i] = crow[i];
    __syncthreads();

    const int e0 = b * ech, e1 = min(e0 + ech, E);
    int e = e0 + (int)threadIdx.x * 2;
    for (; e + 1 < e1; e += 1024) {
        int2   s2 = *reinterpret_cast<const int2*>(src + e);
        int2   d2 = *reinterpret_cast<const int2*>(dst + e);
        float2 w2 = *reinterpret_cast<const float2*>(ew + e);
        unsigned int rd0 = (unsigned int)(d2.x - base);
        if (rd0 < (unsigned int)rse) {
            float w = -dis[s2.x] * w2.x * dis[d2.x];
            int p = atomicAdd(&curL[rd0], 1);
            epk[p] = packedge(s2.x, w);
        }
        unsigned int rd1 = (unsigned int)(d2.y - base);
        if (rd1 < (unsigned int)rse) {
            float w = -dis[s2.y] * w2.y * dis[d2.y];
            int p = atomicAdd(&curL[rd1], 1);
            epk[p] = packedge(s2.y, w);
        }
    }
    if (e < e1) {
        int d = dst[e];
        unsigned int rd_ = (unsigned int)(d - base);
        if (rd_ < (unsigned int)rse) {
            int s = src[e];
            float w = -dis[s] * ew[e] * dis[d];
            int p = atomicAdd(&curL[rd_], 1);
            epk[p] = packedge(s, w);
        }
    }
}

// ---- Kernel 4: gather -> tx/th ROWS; 1 shfl/edge (packed records) ----
__global__ __launch_bounds__(256) void k_gather_bf(
    const unsigned int* __restrict__ xw, const unsigned int* __restrict__ hw,
    const int* __restrict__ off, const int* __restrict__ cntv,
    const unsigned int* __restrict__ epk, const int* __restrict__ hflag,
    unsigned int* __restrict__ txw, unsigned int* __restrict__ thw, int n) {

    int d    = blockIdx.x * 4 + (threadIdx.x >> 6);
    int lane = threadIdx.x & 63;
    if (d >= n) return;
    const bool hasH = (*hflag) != 0;

    int p0 = off[d], p1 = p0 + cntv[d];
    float ax0 = 0.f, ax1 = 0.f, ah0 = 0.f, ah1 = 0.f;

    if (!hasH) {
        for (int base = p0; base < p1; base += 64) {
            int cnt = min(64, p1 - base);
            unsigned int mv = 0u;
            if (lane < cnt) mv = epk[base + lane];
            int k = 0;
            for (; k + 8 <= cnt; k += 8) {
                unsigned int v0 = __shfl(mv, k),     v1 = __shfl(mv, k + 1);
                unsigned int v2 = __shfl(mv, k + 2), v3 = __shfl(mv, k + 3);
                unsigned int v4 = __shfl(mv, k + 4), v5 = __shfl(mv, k + 5);
                unsigned int v6 = __shfl(mv, k + 6), v7 = __shfl(mv, k + 7);
                unsigned int u0 = xw[(v0 & 0xffffu) * 64 + lane];
                unsigned int u1 = xw[(v1 & 0xffffu) * 64 + lane];
                unsigned int u2 = xw[(v2 & 0xffffu) * 64 + lane];
                unsigned int u3 = xw[(v3 & 0xffffu) * 64 + lane];
                unsigned int u4 = xw[(v4 & 0xffffu) * 64 + lane];
                unsigned int u5 = xw[(v5 & 0xffffu) * 64 + lane];
                unsigned int u6 = xw[(v6 & 0xffffu) * 64 + lane];
                unsigned int u7 = xw[(v7 & 0xffffu) * 64 + lane];
                float w0 = bfhi(v0), w1 = bfhi(v1), w2 = bfhi(v2), w3 = bfhi(v3);
                float w4 = bfhi(v4), w5 = bfhi(v5), w6 = bfhi(v6), w7 = bfhi(v7);
                ax0 = fmaf(w0, bflo(u0), ax0); ax1 = fmaf(w0, bfhi(u0), ax1);
                ax0 = fmaf(w1, bflo(u1), ax0); ax1 = fmaf(w1, bfhi(u1), ax1);
                ax0 = fmaf(w2, bflo(u2), ax0); ax1 = fmaf(w2, bfhi(u2), ax1);
                ax0 = fmaf(w3, bflo(u3), ax0); ax1 = fmaf(w3, bfhi(u3), ax1);
                ax0 = fmaf(w4, bflo(u4), ax0); ax1 = fmaf(w4, bfhi(u4), ax1);
                ax0 = fmaf(w5, bflo(u5), ax0); ax1 = fmaf(w5, bfhi(u5), ax1);
                ax0 = fmaf(w6, bflo(u6), ax0); ax1 = fmaf(w6, bfhi(u6), ax1);
                ax0 = fmaf(w7, bflo(u7), ax0); ax1 = fmaf(w7, bfhi(u7), ax1);
            }
            for (; k < cnt; ++k) {
                unsigned int v = __shfl(mv, k);
                unsigned int u = xw[(v & 0xffffu) * 64 + lane];
                float w = bfhi(v);
                ax0 = fmaf(w, bflo(u), ax0); ax1 = fmaf(w, bfhi(u), ax1);
            }
        }
        txw[(size_t)d * 64 + lane] = pack2bf(ax0, ax1);
    } else {
        for (int base = p0; base < p1; base += 64) {
            int cnt = min(64, p1 - base);
            unsigned int mv = 0u;
            if (lane < cnt) mv = epk[base + lane];
            int k = 0;
            for (; k + 4 <= cnt; k += 4) {
                unsigned int v0 = __shfl(mv, k),     v1 = __shfl(mv, k + 1);
                unsigned int v2 = __shfl(mv, k + 2), v3 = __shfl(mv, k + 3);
                unsigned int s0 = (v0 & 0xffffu) * 64 + lane;
                unsigned int s1 = (v1 & 0xffffu) * 64 + lane;
                unsigned int s2 = (v2 & 0xffffu) * 64 + lane;
                unsigned int s3 = (v3 & 0xffffu) * 64 + lane;
                unsigned int u0 = xw[s0], q0 = hw[s0];
                unsigned int u1 = xw[s1], q1 = hw[s1];
                unsigned int u2 = xw[s2], q2 = hw[s2];
                unsigned int u3 = xw[s3], q3 = hw[s3];
                float w0 = bfhi(v0), w1 = bfhi(v1), w2 = bfhi(v2), w3 = bfhi(v3);
                ax0 = fmaf(w0, bflo(u0), ax0); ax1 = fmaf(w0, bfhi(u0), ax1);
                ah0 = fmaf(w0, bflo(q0), ah0); ah1 = fmaf(w0, bfhi(q0), ah1);
                ax0 = fmaf(w1, bflo(u1), ax0); ax1 = fmaf(w1, bfhi(u1), ax1);
                ah0 = fmaf(w1, bflo(q1), ah0); ah1 = fmaf(w1, bfhi(q1), ah1);
                ax0 = fmaf(w2, bflo(u2), ax0); ax1 = fmaf(w2, bfhi(u2), ax1);
                ah0 = fmaf(w2, bflo(q2), ah0); ah1 = fmaf(w2, bfhi(q2), ah1);
                ax0 = fmaf(w3, bflo(u3), ax0); ax1 = fmaf(w3, bfhi(u3), ax1);
                ah0 = fmaf(w3, bflo(q3), ah0); ah1 = fmaf(w3, bfhi(q3), ah1);
            }
            for (; k < cnt; ++k) {
                unsigned int v = __shfl(mv, k);
                unsigned int si = (v & 0xffffu) * 64 + lane;
                unsigned int u = xw[si], q = hw[si];
                float w = bfhi(v);
                ax0 = fmaf(w, bflo(u), ax0); ax1 = fmaf(w, bfhi(u), ax1);
                ah0 = fmaf(w, bflo(q), ah0); ah1 = fmaf(w, bfhi(q), ah1);
            }
        }
        txw[(size_t)d * 64 + lane] = pack2bf(ax0, ax1);
        thw[(size_t)d * 64 + lane] = pack2bf(ah0, ah1);
    }
}

// ---- Kernel 5: GEMM+LSTM; 32-row tiles + prefetch + native-exp epilogue ----
__global__ __launch_bounds__(512) void k_gemm_lstm(
    const unsigned int* __restrict__ xw, const unsigned int* __restrict__ txw,
    const unsigned int* __restrict__ hw, const unsigned int* __restrict__ thw,
    const unsigned short* __restrict__ Wbf, const int* __restrict__ hflag,
    const float* __restrict__ c, const float* __restrict__ bias,
    const float* __restrict__ wc, float* __restrict__ out, int n) {

    __shared__ unsigned int ldsR[32][LDW];
    __shared__ unsigned int ldsG[32][LDW];

    const int rt   = blockIdx.x;
    const int tid  = threadIdx.x;
    const int jj   = tid >> 6;
    const int lane = tid & 63;
    const int r0   = rt * 32;
    const bool hasH = (*hflag) != 0;

    const int col = jj * 16 + (lane & 15);

    // early: prefetch epilogue operands (hide latency under MFMA phase)
    const float wc0 = wc[0 * FD + col], wc1 = wc[1 * FD + col], wc2 = wc[2 * FD + col];
    const float b0  = bias[0 * FD + col], b1 = bias[1 * FD + col];
    const float b2  = bias[2 * FD + col], b3 = bias[3 * FD + col];
    float cv[2][4];
    #pragma unroll
    for (int mi = 0; mi < 2; ++mi)
        #pragma unroll
        for (int q = 0; q < 4; ++q) {
            int r = r0 + mi * 16 + (lane >> 4) * 4 + q;
            cv[mi][q] = (r < n) ? c[(size_t)r * FD + col] : 0.f;
        }

    f32x4 acc[2][4];
    #pragma unroll
    for (int mi = 0; mi < 2; ++mi)
        #pragma unroll
        for (int g = 0; g < 4; ++g)
            acc[mi][g] = (f32x4)0.0f;

    // stage x + tx rows
    {
        int sr = tid >> 4, sc = (tid & 15) * 4;
        uint4 v = make_uint4(0,0,0,0), g = make_uint4(0,0,0,0);
        if (r0 + sr < n) {
            v = *reinterpret_cast<const uint4*>(xw  + (size_t)(r0 + sr) * 64 + sc);
            g = *reinterpret_cast<const uint4*>(txw + (size_t)(r0 + sr) * 64 + sc);
        }
        *reinterpret_cast<uint4*>(&ldsR[sr][sc]) = v;
        *reinterpret_cast<uint4*>(&ldsG[sr][sc]) = g;
    }
    __syncthreads();

    #pragma unroll
    for (int kb = 0; kb < 8; ++kb) {
        bf16x8 a[2], b[4];
        const int c0 = (kb & 3) * 16 + (lane >> 4) * 4;
        #pragma unroll
        for (int mi = 0; mi < 2; ++mi) {
            const unsigned int* lp = (kb < 4) ? &ldsR[mi * 16 + (lane & 15)][c0]
                                              : &ldsG[mi * 16 + (lane & 15)][c0];
            a[mi] = __builtin_bit_cast(bf16x8, *reinterpret_cast<const uint4*>(lp));
        }
        #pragma unroll
        for (int g = 0; g < 4; ++g)
            b[g] = *reinterpret_cast<const bf16x8*>(
                Wbf + ((size_t)(g * 8 + jj) * 16 + kb) * 512 + lane * 8);
        #pragma unroll
        for (int mi = 0; mi < 2; ++mi)
            #pragma unroll
            for (int g = 0; g < 4; ++g)
                acc[mi][g] = __builtin_amdgcn_mfma_f32_16x16x32_bf16(
                                 a[mi], b[g], acc[mi][g], 0, 0, 0);
    }

    if (hasH) {
        __syncthreads();
        {
            int sr = tid >> 4, sc = (tid & 15) * 4;
            uint4 v = make_uint4(0,0,0,0), g = make_uint4(0,0,0,0);
            if (r0 + sr < n) {
                v = *reinterpret_cast<const uint4*>(hw  + (size_t)(r0 + sr) * 64 + sc);
                g = *reinterpret_cast<const uint4*>(thw + (size_t)(r0 + sr) * 64 + sc);
            }
            *reinterpret_cast<uint4*>(&ldsR[sr][sc]) = v;
            *reinterpret_cast<uint4*>(&ldsG[sr][sc]) = g;
        }
        __syncthreads();

        #pragma unroll
        for (int kk = 0; kk < 8; ++kk) {
            const int kb = 8 + kk;
            bf16x8 a[2], b[4];
            const int c0 = (kk & 3) * 16 + (lane >> 4) * 4;
            #pragma unroll
            for (int mi = 0; mi < 2; ++mi) {
                const unsigned int* lp = (kk < 4) ? &ldsR[mi * 16 + (lane & 15)][c0]
                                                  : &ldsG[mi * 16 + (lane & 15)][c0];
                a[mi] = __builtin_bit_cast(bf16x8, *reinterpret_cast<const uint4*>(lp));
            }
            #pragma unroll
            for (int g = 0; g < 4; ++g)
                b[g] = *reinterpret_cast<const bf16x8*>(
                    Wbf + ((size_t)(g * 8 + jj) * 16 + kb) * 512 + lane * 8);
            #pragma unroll
            for (int mi = 0; mi < 2; ++mi)
                #pragma unroll
                for (int g = 0; g < 4; ++g)
                    acc[mi][g] = __builtin_amdgcn_mfma_f32_16x16x32_bf16(
                                     a[mi], b[g], acc[mi][g], 0, 0, 0);
        }
    }

    const size_t NH = (size_t)n * FD;
    #pragma unroll
    for (int mi = 0; mi < 2; ++mi) {
        #pragma unroll
        for (int q = 0; q < 4; ++q) {
            int r = r0 + mi * 16 + (lane >> 4) * 4 + q;
            if (r >= n) continue;
            float cvv = cv[mi][q];
            float gi = acc[mi][0][q] + wc0 * cvv + b0;
            float gf = acc[mi][1][q] + wc1 * cvv + b1;
            float gg = acc[mi][2][q] + b2;
            float iv = fsig(gi);
            float fv = fsig(gf);
            float cn = fv * cvv + iv * ftanh(gg);
            float go = acc[mi][3][q] + wc2 * cn + b3;
            float hn = fsig(go) * ftanh(cn);
            size_t o = (size_t)r * FD + col;
            out[o]          = hn;
            out[NH + o]     = hn;
            out[2 * NH + o] = cn;
        }
    }
}

extern "C" void kernel_launch(void* const* d_in, const int* in_sizes, int n_in,
                              void* d_out, int out_size, void* d_ws, size_t ws_size,
                              hipStream_t stream) {
    const float* x   = (const float*)d_in[0];
    const float* ew  = (const float*)d_in[1];
    const float* h   = (const float*)d_in[2];
    const float* c   = (const float*)d_in[3];
    const float* Wx  = (const float*)d_in[4];
    const float* Wh  = (const float*)d_in[5];
    const float* b   = (const float*)d_in[6];
    const float* wc  = (const float*)d_in[7];
    const int*   src = (const int*)d_in[8];
    const int*   dst = (const int*)d_in[9];

    const int n = in_sizes[0] / FD;   // 20000  (<= NMAX, and < 65536 for u16 src)
    const int E = in_sizes[1];        // 640000

    const int Mpad = (n + 31) & ~31;              // 32-row tiles
    const int ech  = (E + NB - 1) / NB;           // 5000
    const int rsh  = (n + NRH - 1) / NRH;         // 10000
    const int rsf  = (n + NRF - 1) / NRF;         // 10000
    const int n16  = n * 16;
    const int cvb  = (n16 + 511) / 512;           // cvt section blocks
    const int npf  = (n + 127) / 128;             // fold blocks

    // ---- workspace layout ----
    float* dis      = (float*)d_ws;                        // n
    int*   cnt      = (int*)(dis + n);                     // n
    int*   off      = cnt + n;                             // n+4
    int*   hflag    = off + n + 4;                         // 4
    int*   cursor   = hflag + 4;                           // 4
    int*   flagpart = cursor + 4;                          // 1280 (pad)
    unsigned int* epk = (unsigned int*)(flagpart + 1280);  // E (packed u16 src + bf16 w)
    unsigned int* xw  = epk + E;                           // n*64
    unsigned int* hw  = xw + (size_t)n * 64;               // n*64
    unsigned int* txw = hw + (size_t)n * 64;               // n*64
    unsigned int* thw = txw + (size_t)n * 64;              // n*64
    unsigned short* Wbf = (unsigned short*)(thw + (size_t)n * 64); // 512*512
    int*   curb     = (int*)(Wbf + 512 * 512);             // NB*n
    float* deg_priv = (float*)(curb + (size_t)NB * n);     // NB*n
    unsigned short* cnt_priv = (unsigned short*)(deg_priv + (size_t)NB * n); // NB*n

    k_front<<<NB * NRH + cvb + 64, 512, 0, stream>>>(
        ew, src, dst, deg_priv, cnt_priv, cursor, hflag,
        x, h, Wx, Wh, xw, hw, Wbf, flagpart,
        E, n, ech, rsh, n16, cvb);
    k_fold<<<npf, 512, 0, stream>>>(deg_priv, cnt_priv, dis, cnt, off, curb,
                                    cursor, n);
    k_fill_lds<<<NB * NRF, 512, 0, stream>>>(ew, src, dst, dis, curb, epk,
                                             flagpart, hflag, E, n, ech, rsf, cvb);
    k_gather_bf<<<(n + 3) / 4, 256, 0, stream>>>(xw, hw, off, cnt, epk, hflag,
                                                 txw, thw, n);
    k_gemm_lstm<<<Mpad / 32, 512, 0, stream>>>(xw, txw, hw, thw, Wbf, hflag,
                                               c, b, wc, (float*)d_out, n);
}